// Round 3
// baseline (1317.159 us; speedup 1.0000x reference)
//
#include <hip/hip_runtime.h>

typedef unsigned short u16;
typedef __bf16 bf16x8 __attribute__((ext_vector_type(8)));
typedef float floatx4 __attribute__((ext_vector_type(4)));

#define NE 800000
#define NN 50000
#define CHUNKS 32
#define CHUNK (NE / CHUNKS)   // 25000
#define WIN 25000             // histogram window per segment (2 windows per array)
#define NBKT 32               // src-range buckets for the sweep
#define DPW 8                 // dsts per wave in sweep kernels

__device__ __forceinline__ float b2f(unsigned u) { return __uint_as_float(u << 16); }
__device__ __forceinline__ u16 f2b(float f) {
  unsigned x = __float_as_uint(f);
  x += 0x7fffu + ((x >> 16) & 1u);
  return (u16)(x >> 16);
}
__device__ __forceinline__ int clampi(int s) {
  return (s < 0) ? 0 : (s > NN - 1 ? NN - 1 : s);
}

// ---------------- bucket sort of edges by src range (32 buckets) ----------------
__global__ __launch_bounds__(256) void k_bcount(const int* __restrict__ s0,
                                                const int* __restrict__ s1,
                                                const int* __restrict__ s2,
                                                unsigned* __restrict__ bcnt) {
  __shared__ unsigned h[NBKT];
  int c = blockIdx.x, r = blockIdx.y, t = threadIdx.x;
  if (t < NBKT) h[t] = 0;
  __syncthreads();
  const int* s = (r == 0) ? s0 : (r == 1) ? s1 : s2;
  int st = c * CHUNK, en = st + CHUNK;
  for (int e = st + t; e < en; e += 256) {
    unsigned b = (unsigned)(clampi(s[e]) * NBKT) / (unsigned)NN;
    atomicAdd(&h[b], 1u);
  }
  __syncthreads();
  if (t < NBKT) bcnt[(r * CHUNKS + c) * NBKT + t] = h[t];
}

__global__ __launch_bounds__(128) void k_bscan(const unsigned* __restrict__ bcnt,
                                               unsigned* __restrict__ bbase) {
  __shared__ unsigned tot[96];
  int t = threadIdx.x;
  if (t < 96) {
    int r = t / NBKT, b = t % NBKT;
    unsigned run = 0;
    for (int c = 0; c < CHUNKS; ++c) {
      bbase[(r * CHUNKS + c) * NBKT + b] = run;
      run += bcnt[(r * CHUNKS + c) * NBKT + b];
    }
    tot[t] = run;
  }
  __syncthreads();
  if (t < 96) {
    int r = t / NBKT, b = t % NBKT;
    unsigned base = 0;
    for (int b2 = 0; b2 < b; ++b2) base += tot[r * NBKT + b2];
    for (int c = 0; c < CHUNKS; ++c) bbase[(r * CHUNKS + c) * NBKT + b] += base;
  }
}

__global__ __launch_bounds__(256) void k_bscatter(
    const int* __restrict__ s0, const int* __restrict__ d0_,
    const int* __restrict__ s1, const int* __restrict__ d1_,
    const int* __restrict__ s2, const int* __restrict__ d2_,
    const unsigned* __restrict__ bbase, int* __restrict__ edgS) {
  __shared__ unsigned rk[NBKT];
  int c = blockIdx.x, r = blockIdx.y, t = threadIdx.x;
  if (t < NBKT) rk[t] = 0;
  __syncthreads();
  const int* s = (r == 0) ? s0 : (r == 1) ? s1 : s2;
  const int* d = (r == 0) ? d0_ : (r == 1) ? d1_ : d2_;
  int* srcS = edgS + r * NE;
  int* dstS = edgS + 3 * NE + r * NE;
  const unsigned* bb = bbase + (r * CHUNKS + c) * NBKT;
  int st = c * CHUNK, en = st + CHUNK;
  for (int e = st + t; e < en; e += 256) {
    int sv = clampi(s[e]);
    unsigned b = (unsigned)(sv * NBKT) / (unsigned)NN;
    unsigned pos = atomicAdd(&rk[b], 1u);
    unsigned slot = bb[b] + pos;
    srcS[slot] = sv;
    dstS[slot] = d[e];
  }
}

// ---------------- histogram degrees (LDS, atomic-free in HBM) ----------------
__global__ __launch_bounds__(256) void k_hist(
    const int* __restrict__ dF, const int* __restrict__ dRB, const int* __restrict__ dR,
    const int* __restrict__ sF, const int* __restrict__ sR, const int* __restrict__ sRB,
    u16* __restrict__ partial) {
  __shared__ unsigned h[WIN / 2];          // packed u16 pairs, 50 KB
  int c = blockIdx.x, g = blockIdx.y, t = threadIdx.x;
  int a = g >> 1, lo = (g & 1) * WIN;
  for (int i = t; i < WIN / 2; i += 256) h[i] = 0;
  __syncthreads();
  const int* idx = (a == 0) ? dF : (a == 1) ? dRB : (a == 2) ? dR
                 : (a == 3) ? sF : (a == 4) ? sR : sRB;
  int st = c * CHUNK, en = st + CHUNK;
  for (int e = st + t; e < en; e += 256) {
    unsigned u = (unsigned)(idx[e] - lo);
    if (u < (unsigned)WIN) atomicAdd(&h[u >> 1], 1u << ((u & 1) * 16));
  }
  __syncthreads();
  unsigned* po = (unsigned*)(partial + ((size_t)g * CHUNKS + c) * WIN);
  for (int i = t; i < WIN / 2; i += 256) po[i] = h[i];
}

__global__ __launch_bounds__(256) void k_hreduce(const u16* __restrict__ partial,
                                                 u16* __restrict__ chunkcum,
                                                 int* __restrict__ DI) {
  int i = blockIdx.x * 256 + threadIdx.x;
  int g = blockIdx.y;
  if (i >= WIN) return;
  const u16* p = partial + (size_t)g * CHUNKS * WIN + i;
  u16* cc = chunkcum + (size_t)g * CHUNKS * WIN + i;   // only meaningful for g<6
  int run = 0;
#pragma unroll
  for (int c = 0; c < CHUNKS; ++c) {
    if (g < 6) cc[(size_t)c * WIN] = (u16)run;
    run += p[(size_t)c * WIN];
  }
  int a = g >> 1, r = g & 1;
  DI[a * NN + r * WIN + i] = run;
}

__global__ __launch_bounds__(1024) void k_scan1(const int* __restrict__ cnt,
                                                int* __restrict__ offs,
                                                int* __restrict__ partials) {
  __shared__ int tmp[1024];
  int t = threadIdx.x, i = blockIdx.x * 1024 + t;
  int c = (i < 150000) ? cnt[i] : 0;
  tmp[t] = c; __syncthreads();
  for (int off = 1; off < 1024; off <<= 1) {
    int v = (t >= off) ? tmp[t - off] : 0;
    __syncthreads();
    tmp[t] += v;
    __syncthreads();
  }
  if (i <= 150000) offs[i] = tmp[t] - c;
  if (t == 1023) partials[blockIdx.x] = tmp[1023];
}

__global__ __launch_bounds__(256) void k_scan2(int* __restrict__ partials) {
  __shared__ int tmp[256];
  int t = threadIdx.x;
  int c = (t < 147) ? partials[t] : 0;
  tmp[t] = c; __syncthreads();
  for (int off = 1; off < 256; off <<= 1) {
    int v = (t >= off) ? tmp[t - off] : 0;
    __syncthreads();
    tmp[t] += v;
    __syncthreads();
  }
  if (t < 147) partials[t] = tmp[t] - c;
}

__global__ __launch_bounds__(1024) void k_scan3(int* __restrict__ offs,
                                                const int* __restrict__ partials) {
  int i = blockIdx.x * 1024 + threadIdx.x;
  if (i <= 150000) offs[i] += partials[blockIdx.x];
}

__global__ void k_rsq(int* __restrict__ DI, int n) {
  int i = blockIdx.x * 256 + threadIdx.x;
  if (i < n) {
    float v = (float)DI[i];
    ((float*)DI)[i] = rsqrtf(fmaxf(v, 1.f));
  }
}

// CSR scatter, atomic-free: slot = offs[dst] + chunkcum[dst] + LDS-rank
__global__ __launch_bounds__(256) void k_scatlds(
    const int* __restrict__ sF, const int* __restrict__ dF,
    const int* __restrict__ sRB, const int* __restrict__ dRB,
    const int* __restrict__ sR, const int* __restrict__ dR,
    const int* __restrict__ offs, const u16* __restrict__ chunkcum,
    int* __restrict__ csr) {
  __shared__ unsigned h[WIN / 2];          // rank counters, 50 KB
  int c = blockIdx.x, g = blockIdx.y, t = threadIdx.x;
  int a = g >> 1, lo = (g & 1) * WIN;
  for (int i = t; i < WIN / 2; i += 256) h[i] = 0;
  __syncthreads();
  const int* s = (a == 0) ? sF : (a == 1) ? sRB : sR;
  const int* d = (a == 0) ? dF : (a == 1) ? dRB : dR;
  int base = a * NN;
  const u16* cc = chunkcum + ((size_t)g * CHUNKS + c) * WIN;
  int st = c * CHUNK, en = st + CHUNK;
  for (int e = st + t; e < en; e += 256) {
    int dd = d[e];
    unsigned u = (unsigned)(dd - lo);
    if (u < (unsigned)WIN) {
      unsigned sh = (u & 1) * 16;
      unsigned old = atomicAdd(&h[u >> 1], 1u << sh);
      int r = (int)((old >> sh) & 0xffffu);
      csr[offs[base + dd] + (int)cc[u] + r] = s[e];
    }
  }
}

// 6 weight transposes fused: dst[n*256+k] = f2b(src[k*N+n]), K=256 rows
__global__ void k_tpose6(const float* __restrict__ W1f, const float* __restrict__ W1rt,
                         const float* __restrict__ W1rb, const float* __restrict__ W2f,
                         const float* __restrict__ W2rt, const float* __restrict__ W2rb,
                         u16* __restrict__ Bt1u, u16* __restrict__ Bt1i,
                         u16* __restrict__ Bt2u, u16* __restrict__ Bt2i) {
  int a = blockIdx.y;
  const float* src; u16* dst; int N;
  switch (a) {
    case 0: src = W1f;  dst = Bt1u;         N = 256; break;
    case 1: src = W1rt; dst = Bt1u + 65536; N = 256; break;
    case 2: src = W1rb; dst = Bt1i;         N = 256; break;
    case 3: src = W2f;  dst = Bt2u;         N = 128; break;
    case 4: src = W2rt; dst = Bt2u + 32768; N = 128; break;
    default: src = W2rb; dst = Bt2i;        N = 128; break;
  }
  int i = blockIdx.x * 256 + threadIdx.x;
  if (i < 256 * N) {
    int n = i >> 8, k = i & 255;
    dst[i] = f2b(src[(size_t)k * N + n]);
  }
}

// ---------------- GEMM: C[M,Ntot] = A[M,256] @ Bt[Ntot,256]^T, epilogue row-scale ----------------
template <bool AF32>
__global__ __launch_bounds__(256) void k_gemm(
    const void* __restrict__ A, const u16* __restrict__ Bt, u16* __restrict__ C,
    int M, int Ntot, const float* __restrict__ rs0, const float* __restrict__ rs1, int splitN) {
  __shared__ alignas(16) u16 As[128 * 64];
  __shared__ alignas(16) u16 Bs[128 * 64];
  const int tid = threadIdx.x;
  const int mBase = blockIdx.x * 128;
  const int nBase = blockIdx.y * 128;
  const int w = tid >> 6, lane = tid & 63;
  const int wm = w & 1, wn = w >> 1;
  const int lr = lane & 15, quad = lane >> 4;
  floatx4 acc[4][4] = {};
  for (int kb = 0; kb < 256; kb += 64) {
    uint4 va[4], vb[4];
#pragma unroll
    for (int c = 0; c < 4; ++c) {
      int idx = c * 256 + tid;
      int row = idx >> 3;
      int col8 = (idx & 7) * 8;
      int gr = mBase + row; if (gr > M - 1) gr = M - 1;
      if constexpr (AF32) {
        const float* ap = (const float*)A + (size_t)gr * 256 + kb + col8;
        float4 f0 = *(const float4*)ap;
        float4 f1 = *(const float4*)(ap + 4);
        va[c] = make_uint4(
            (unsigned)f2b(f0.x) | ((unsigned)f2b(f0.y) << 16),
            (unsigned)f2b(f0.z) | ((unsigned)f2b(f0.w) << 16),
            (unsigned)f2b(f1.x) | ((unsigned)f2b(f1.y) << 16),
            (unsigned)f2b(f1.z) | ((unsigned)f2b(f1.w) << 16));
      } else {
        va[c] = *(const uint4*)((const u16*)A + (size_t)gr * 256 + kb + col8);
      }
      vb[c] = *(const uint4*)(Bt + (size_t)(nBase + row) * 256 + kb + col8);
    }
#pragma unroll
    for (int c = 0; c < 4; ++c) {
      int idx = c * 256 + tid;
      *(uint4*)(&As[idx * 8]) = va[c];
      *(uint4*)(&Bs[idx * 8]) = vb[c];
    }
    __syncthreads();
#pragma unroll
    for (int ks = 0; ks < 2; ++ks) {
      bf16x8 fa[4], fb[4];
#pragma unroll
      for (int m = 0; m < 4; ++m)
        fa[m] = *(const bf16x8*)(&As[(wm * 64 + m * 16 + lr) * 64 + ks * 32 + quad * 8]);
#pragma unroll
      for (int n = 0; n < 4; ++n)
        fb[n] = *(const bf16x8*)(&Bs[(wn * 64 + n * 16 + lr) * 64 + ks * 32 + quad * 8]);
#pragma unroll
      for (int m = 0; m < 4; ++m)
#pragma unroll
        for (int n = 0; n < 4; ++n)
          acc[m][n] = __builtin_amdgcn_mfma_f32_16x16x32_bf16(fa[m], fb[n], acc[m][n], 0, 0, 0);
    }
    __syncthreads();
  }
#pragma unroll
  for (int n = 0; n < 4; ++n) {
    int cg = nBase + wn * 64 + n * 16 + lr;
    const float* rs = (cg < splitN) ? rs0 : rs1;
#pragma unroll
    for (int m = 0; m < 4; ++m) {
      int rb_ = mBase + wm * 64 + m * 16 + quad * 4;
#pragma unroll
      for (int r = 0; r < 4; ++r) {
        int rg = rb_ + r;
        if (rg < M) C[(size_t)rg * Ntot + cg] = f2b(acc[m][n][r] * rs[rg]);
      }
    }
  }
}

// ---------------- SpMM sweep (CSR by dst, lists bucket-sorted by src) ----------------
// Fixed-point round-robin over DPW dsts per wave: each iteration tests all
// walkers against lim (registers only), issues up to DPW row loads + DPW
// next-csr prefetches per relation (all independent -> deep MLP), then
// accumulates and advances. Loop control never waits on memory.

template <int VEC>
__device__ __forceinline__ uint2 ldrow(const u16* __restrict__ p) {
  uint2 r;
  if constexpr (VEC == 4) {
    r = *(const uint2*)p;
  } else {
    r.x = *(const unsigned*)p;
    r.y = 0u;
  }
  return r;
}

template <int VEC>
__device__ __forceinline__ void accum(float* acc, uint2 v) {
  acc[0] += b2f(v.x & 0xffffu);
  acc[1] += b2f(v.x >> 16);
  if constexpr (VEC == 4) {
    acc[2] += b2f(v.y & 0xffffu);
    acc[3] += b2f(v.y >> 16);
  }
}

template <int VEC, bool RELU, bool OUT32>
__global__ __launch_bounds__(64) void k_sweep2(
    const u16* __restrict__ fA, int sA, int oA,
    const u16* __restrict__ fB, int sB, int oB,
    const int* __restrict__ csr, const int* __restrict__ offs, int baseA, int baseB,
    const float* __restrict__ rsA, const float* __restrict__ rsB,
    const float* __restrict__ bA, const float* __restrict__ bB,
    void* __restrict__ outv, size_t outBase, int sOut) {
  int lane = threadIdx.x;
  int d0 = blockIdx.x * DPW;
  int eA[DPW], nA[DPW], eB[DPW], nB[DPW];
  int sAv[DPW], sBv[DPW];                  // next src value (clamped) or INT_MAX
  float aA[DPW][VEC] = {}, aB[DPW][VEC] = {};
#pragma unroll
  for (int i = 0; i < DPW; ++i) {
    int d = d0 + i;
    int dd = (d < NN) ? d : NN - 1;
    bool ok = d < NN;
    eA[i] = offs[baseA + dd]; nA[i] = ok ? offs[baseA + dd + 1] : eA[i];
    eB[i] = offs[baseB + dd]; nB[i] = ok ? offs[baseB + dd + 1] : eB[i];
    sAv[i] = (eA[i] < nA[i]) ? clampi(csr[eA[i]]) : 0x7fffffff;
    sBv[i] = (eB[i] < nB[i]) ? clampi(csr[eB[i]]) : 0x7fffffff;
  }
  const u16* pA = fA + oA + lane * VEC;
  const u16* pB = fB + oB + lane * VEC;
  for (int b = 0; b < NBKT; ++b) {
    int lim = ((b + 1) * NN + NBKT - 1) / NBKT;
    for (;;) {
      uint2 vA[DPW], vB[DPW];
      int nxA[DPW], nxB[DPW];
      bool gA[DPW], gB[DPW];
      bool any = false;
#pragma unroll
      for (int i = 0; i < DPW; ++i) {
        gA[i] = sAv[i] < lim;
        gB[i] = sBv[i] < lim;
        any = any | gA[i] | gB[i];
        if (gA[i]) {
          vA[i] = ldrow<VEC>(pA + (size_t)sAv[i] * sA);
          nxA[i] = (eA[i] + 1 < nA[i]) ? clampi(csr[eA[i] + 1]) : 0x7fffffff;
        }
        if (gB[i]) {
          vB[i] = ldrow<VEC>(pB + (size_t)sBv[i] * sB);
          nxB[i] = (eB[i] + 1 < nB[i]) ? clampi(csr[eB[i] + 1]) : 0x7fffffff;
        }
      }
      if (!any) break;
#pragma unroll
      for (int i = 0; i < DPW; ++i) {
        if (gA[i]) { accum<VEC>(aA[i], vA[i]); ++eA[i]; sAv[i] = nxA[i]; }
        if (gB[i]) { accum<VEC>(aB[i], vB[i]); ++eB[i]; sBv[i] = nxB[i]; }
      }
    }
  }
  float bva[VEC], bvb[VEC];
#pragma unroll
  for (int v = 0; v < VEC; ++v) { bva[v] = bA[lane * VEC + v]; bvb[v] = bB[lane * VEC + v]; }
#pragma unroll
  for (int i = 0; i < DPW; ++i) {
    int d = d0 + i;
    if (d >= NN) break;
    float ra = rsA[d], rb = rsB[d];
    size_t o = outBase + (size_t)d * sOut + lane * VEC;
#pragma unroll
    for (int v = 0; v < VEC; ++v) {
      float x = 0.5f * (aA[i][v] * ra + bva[v] + aB[i][v] * rb + bvb[v]);
      if (RELU) x = fmaxf(x, 0.f);
      if (OUT32) ((float*)outv)[o + v] = x;
      else       ((u16*)outv)[o + v] = f2b(x);
    }
  }
}

template <int VEC, bool RELU, bool OUT32>
__global__ __launch_bounds__(64) void k_sweep1(
    const u16* __restrict__ fA, int sA, int oA,
    const int* __restrict__ csr, const int* __restrict__ offs, int baseA,
    const float* __restrict__ rsA, const float* __restrict__ bA,
    void* __restrict__ outv, size_t outBase, int sOut) {
  int lane = threadIdx.x;
  int d0 = blockIdx.x * DPW;
  int eA[DPW], nA[DPW], sAv[DPW];
  float aA[DPW][VEC] = {};
#pragma unroll
  for (int i = 0; i < DPW; ++i) {
    int d = d0 + i;
    int dd = (d < NN) ? d : NN - 1;
    bool ok = d < NN;
    eA[i] = offs[baseA + dd]; nA[i] = ok ? offs[baseA + dd + 1] : eA[i];
    sAv[i] = (eA[i] < nA[i]) ? clampi(csr[eA[i]]) : 0x7fffffff;
  }
  const u16* pA = fA + oA + lane * VEC;
  for (int b = 0; b < NBKT; ++b) {
    int lim = ((b + 1) * NN + NBKT - 1) / NBKT;
    for (;;) {
      uint2 vA[DPW];
      int nxA[DPW];
      bool gA[DPW];
      bool any = false;
#pragma unroll
      for (int i = 0; i < DPW; ++i) {
        gA[i] = sAv[i] < lim;
        any = any | gA[i];
        if (gA[i]) {
          vA[i] = ldrow<VEC>(pA + (size_t)sAv[i] * sA);
          nxA[i] = (eA[i] + 1 < nA[i]) ? clampi(csr[eA[i] + 1]) : 0x7fffffff;
        }
      }
      if (!any) break;
#pragma unroll
      for (int i = 0; i < DPW; ++i) {
        if (gA[i]) { accum<VEC>(aA[i], vA[i]); ++eA[i]; sAv[i] = nxA[i]; }
      }
    }
  }
  float bva[VEC];
#pragma unroll
  for (int v = 0; v < VEC; ++v) bva[v] = bA[lane * VEC + v];
#pragma unroll
  for (int i = 0; i < DPW; ++i) {
    int d = d0 + i;
    if (d >= NN) break;
    float ra = rsA[d];
    size_t o = outBase + (size_t)d * sOut + lane * VEC;
#pragma unroll
    for (int v = 0; v < VEC; ++v) {
      float x = aA[i][v] * ra + bva[v];
      if (RELU) x = fmaxf(x, 0.f);
      if (OUT32) ((float*)outv)[o + v] = x;
      else       ((u16*)outv)[o + v] = f2b(x);
    }
  }
}

extern "C" void kernel_launch(void* const* d_in, const int* in_sizes, int n_in,
                              void* d_out, int out_size, void* d_ws, size_t ws_size,
                              hipStream_t stream) {
  (void)in_sizes; (void)n_in; (void)out_size;
  const float* x_user = (const float*)d_in[0];
  const float* x_item = (const float*)d_in[1];
  const float* W1f  = (const float*)d_in[2];  const float* b1f  = (const float*)d_in[3];
  const float* W1rt = (const float*)d_in[4];  const float* b1rt = (const float*)d_in[5];
  const float* W1rb = (const float*)d_in[6];  const float* b1rb = (const float*)d_in[7];
  const float* W2f  = (const float*)d_in[8];  const float* b2fo = (const float*)d_in[9];
  const float* W2rt = (const float*)d_in[10]; const float* b2rt = (const float*)d_in[11];
  const float* W2rb = (const float*)d_in[12]; const float* b2rb = (const float*)d_in[13];
  const int* srcF  = (const int*)d_in[14]; const int* dstF  = (const int*)d_in[15];
  const int* srcR  = (const int*)d_in[16]; const int* dstR  = (const int*)d_in[17];
  const int* srcRB = (const int*)d_in[18]; const int* dstRB = (const int*)d_in[19];

  // ---- workspace layout (bytes) ----
  // DI/R   : [0, 1200000)           300000 i32 -> f32 in place
  // offs   : [1800064, 2400068)     150001 i32
  // csr    : [2400128, 12000128)    2400000 i32  (first 588 B double as scan partials)
  // Bt1u/Bt1i/Bt2u/Bt2i bf16        [12000128, 12589952)
  // featA  : [12589952, 63789952)   [50000,512] bf16
  //          scratch (pre-GEMM): hpart u16 12*32*25000 @featA+0 (19.2MB),
  //                              chunkcum u16 6*32*25000 @featA+19.2MB (9.6MB),
  //                              edgS i32 6*800000 @featA+28.8MB (19.2MB),
  //                              bcnt/bbase u32 @ws+60589952 (24KB)
  // featB  : [63789952, 89389952)   [50000,256]
  // h_u    : [89389952, 114989952)  [50000,256]
  if (ws_size < 114989952u) return;

  char* ws = (char*)d_ws;
  int*   DI     = (int*)ws;
  float* R      = (float*)ws;
  int*   offs   = (int*)(ws + 1800064);
  int*   csr    = (int*)(ws + 2400128);
  int*   partials = csr;                    // scan scratch, free until k_scatlds
  u16*   Bt1u   = (u16*)(ws + 12000128);
  u16*   Bt1i   = (u16*)(ws + 12262272);
  u16*   Bt2u   = (u16*)(ws + 12393344);
  u16*   Bt2i   = (u16*)(ws + 12524416);
  u16*   featA  = (u16*)(ws + 12589952);
  u16*   featB  = (u16*)(ws + 63789952);
  u16*   h_u    = (u16*)(ws + 89389952);
  u16*   h_i    = featB;
  u16*   feat2rb = featA + (size_t)50000 * 256;
  u16*   hpart  = featA;                    // 12*32*25000 u16, dead before GEMM1
  u16*   chunkcum = featA + (size_t)12 * CHUNKS * WIN;  // 6*32*25000 u16
  int*   edgS   = (int*)(ws + 41389952);    // 6*800000 i32 bucket-sorted edges
  unsigned* bcnt  = (unsigned*)(ws + 60589952);
  unsigned* bbase = bcnt + 3 * CHUNKS * NBKT;

  // bucket-sort edges by src range (per relation)
  k_bcount<<<dim3(CHUNKS, 3), 256, 0, stream>>>(srcF, srcRB, srcR, bcnt);
  k_bscan<<<1, 128, 0, stream>>>(bcnt, bbase);
  k_bscatter<<<dim3(CHUNKS, 3), 256, 0, stream>>>(srcF, dstF, srcRB, dstRB, srcR, dstR,
                                                  bbase, edgS);
  int* srcS_F  = edgS;            int* dstS_F  = edgS + 3 * NE;
  int* srcS_RB = edgS + NE;       int* dstS_RB = edgS + 4 * NE;
  int* srcS_R  = edgS + 2 * NE;   int* dstS_R  = edgS + 5 * NE;

  k_hist<<<dim3(CHUNKS, 12), 256, 0, stream>>>(dstS_F, dstS_RB, dstS_R, srcF, srcR, srcRB, hpart);
  k_hreduce<<<dim3(98, 12), 256, 0, stream>>>(hpart, chunkcum, DI);
  k_scan1<<<147, 1024, 0, stream>>>(DI, offs, partials);
  k_scan2<<<1, 256, 0, stream>>>(partials);
  k_scan3<<<147, 1024, 0, stream>>>(offs, partials);
  k_rsq<<<(300000 + 255) / 256, 256, 0, stream>>>(DI, 300000);
  k_scatlds<<<dim3(CHUNKS, 6), 256, 0, stream>>>(srcS_F, dstS_F, srcS_RB, dstS_RB,
                                                 srcS_R, dstS_R, offs, chunkcum, csr);
  k_tpose6<<<dim3(256, 6), 256, 0, stream>>>(W1f, W1rt, W1rb, W2f, W2rt, W2rb,
                                             Bt1u, Bt1i, Bt2u, Bt2i);

  const int SWG = (NN + DPW - 1) / DPW;     // 6250 blocks of 1 wave

  // layer 1 GEMMs (rsqrt(out_deg) row scale commutes with @W; applied in epilogue)
  k_gemm<true><<<dim3(391, 4), 256, 0, stream>>>(x_user, Bt1u, featA, 50000, 512,
                                                 R + 150000, R + 200000, 256);
  k_gemm<true><<<dim3(391, 2), 256, 0, stream>>>(x_item, Bt1i, featB, 50000, 256,
                                                 R + 250000, R + 250000, 256);
  // layer 1 aggregation (bf16 stores into ws)
  k_sweep2<4, true, false><<<SWG, 64, 0, stream>>>(featA, 512, 0, featB, 256, 0,
                                                   csr, offs, 0, 50000,
                                                   R, R + 50000, b1f, b1rb, h_u, 0, 256);
  k_sweep1<4, true, false><<<SWG, 64, 0, stream>>>(featA, 512, 256, csr, offs, 100000,
                                                   R + 100000, b1rt, h_i, 0, 256);
  // layer 2 GEMMs (A = bf16 ws buffers)
  k_gemm<false><<<dim3(391, 2), 256, 0, stream>>>(h_u, Bt2u, featA, 50000, 256,
                                                  R + 150000, R + 200000, 128);
  k_gemm<false><<<dim3(391, 1), 256, 0, stream>>>(h_i, Bt2i, feat2rb, 50000, 128,
                                                  R + 250000, R + 250000, 128);
  // layer 2 aggregation -> d_out (fp32)
  k_sweep2<2, false, true><<<SWG, 64, 0, stream>>>(featA, 256, 0, feat2rb, 128, 0,
                                                   csr, offs, 0, 50000,
                                                   R, R + 50000, b2fo, b2rb, d_out, 0, 128);
  k_sweep1<2, false, true><<<SWG, 64, 0, stream>>>(featA, 256, 128, csr, offs, 100000,
                                                   R + 100000, b2rt, d_out,
                                                   (size_t)50000 * 128, 128);
}

// Round 4
// 1010.881 us; speedup vs baseline: 1.3030x; 1.3030x over previous
//
#include <hip/hip_runtime.h>

typedef unsigned short u16;
typedef __bf16 bf16x8 __attribute__((ext_vector_type(8)));
typedef float floatx4 __attribute__((ext_vector_type(4)));

#define NE 800000
#define NN 50000
#define CHUNKS 32
#define CHUNK (NE / CHUNKS)   // 25000
#define WIN 25000             // histogram window per segment (2 windows per array)

__device__ __forceinline__ float b2f(unsigned u) { return __uint_as_float(u << 16); }
__device__ __forceinline__ u16 f2b(float f) {
  unsigned x = __float_as_uint(f);
  x += 0x7fffu + ((x >> 16) & 1u);
  return (u16)(x >> 16);
}
__device__ __forceinline__ int clampi(int s) {
  return (s < 0) ? 0 : (s > NN - 1 ? NN - 1 : s);
}

// ---------------- histogram degrees (LDS, atomic-free in HBM) ----------------
// segment g in [0,12): array a=g>>1, window r=g&1 covering idx in [r*WIN,(r+1)*WIN)
// arrays: 0=dstF 1=dstRB 2=dstR 3=srcF 4=srcR 5=srcRB  (matches DI layout below)
__global__ __launch_bounds__(256) void k_hist(
    const int* __restrict__ dF, const int* __restrict__ dRB, const int* __restrict__ dR,
    const int* __restrict__ sF, const int* __restrict__ sR, const int* __restrict__ sRB,
    u16* __restrict__ partial) {
  __shared__ unsigned h[WIN / 2];          // packed u16 pairs, 50 KB
  int c = blockIdx.x, g = blockIdx.y, t = threadIdx.x;
  int a = g >> 1, lo = (g & 1) * WIN;
  for (int i = t; i < WIN / 2; i += 256) h[i] = 0;
  __syncthreads();
  const int* idx = (a == 0) ? dF : (a == 1) ? dRB : (a == 2) ? dR
                 : (a == 3) ? sF : (a == 4) ? sR : sRB;
  int st = c * CHUNK, en = st + CHUNK;
  for (int e = st + t; e < en; e += 256) {
    unsigned u = (unsigned)(idx[e] - lo);
    if (u < (unsigned)WIN) atomicAdd(&h[u >> 1], 1u << ((u & 1) * 16));
  }
  __syncthreads();
  unsigned* po = (unsigned*)(partial + ((size_t)g * CHUNKS + c) * WIN);
  for (int i = t; i < WIN / 2; i += 256) po[i] = h[i];
}

// partials -> DI counts; byproduct: exclusive per-chunk cumsum for relations (g<6)
__global__ __launch_bounds__(256) void k_hreduce(const u16* __restrict__ partial,
                                                 u16* __restrict__ chunkcum,
                                                 int* __restrict__ DI) {
  int i = blockIdx.x * 256 + threadIdx.x;
  int g = blockIdx.y;
  if (i >= WIN) return;
  const u16* p = partial + (size_t)g * CHUNKS * WIN + i;
  u16* cc = chunkcum + (size_t)g * CHUNKS * WIN + i;   // only meaningful for g<6
  int run = 0;
#pragma unroll
  for (int c = 0; c < CHUNKS; ++c) {
    if (g < 6) cc[(size_t)c * WIN] = (u16)run;
    run += p[(size_t)c * WIN];
  }
  int a = g >> 1, r = g & 1;
  DI[a * NN + r * WIN + i] = run;
}

// parallel exclusive scan over 150000 counts -> offs[0..150000]
__global__ __launch_bounds__(1024) void k_scan1(const int* __restrict__ cnt,
                                                int* __restrict__ offs,
                                                int* __restrict__ partials) {
  __shared__ int tmp[1024];
  int t = threadIdx.x, i = blockIdx.x * 1024 + t;
  int c = (i < 150000) ? cnt[i] : 0;
  tmp[t] = c; __syncthreads();
  for (int off = 1; off < 1024; off <<= 1) {
    int v = (t >= off) ? tmp[t - off] : 0;
    __syncthreads();
    tmp[t] += v;
    __syncthreads();
  }
  if (i <= 150000) offs[i] = tmp[t] - c;
  if (t == 1023) partials[blockIdx.x] = tmp[1023];
}

__global__ __launch_bounds__(256) void k_scan2(int* __restrict__ partials) {
  __shared__ int tmp[256];
  int t = threadIdx.x;
  int c = (t < 147) ? partials[t] : 0;
  tmp[t] = c; __syncthreads();
  for (int off = 1; off < 256; off <<= 1) {
    int v = (t >= off) ? tmp[t - off] : 0;
    __syncthreads();
    tmp[t] += v;
    __syncthreads();
  }
  if (t < 147) partials[t] = tmp[t] - c;
}

__global__ __launch_bounds__(1024) void k_scan3(int* __restrict__ offs,
                                                const int* __restrict__ partials) {
  int i = blockIdx.x * 1024 + threadIdx.x;
  if (i <= 150000) offs[i] += partials[blockIdx.x];
}

__global__ void k_rsq(int* __restrict__ DI, int n) {
  int i = blockIdx.x * 256 + threadIdx.x;
  if (i < n) {
    float v = (float)DI[i];
    ((float*)DI)[i] = rsqrtf(fmaxf(v, 1.f));
  }
}

// CSR scatter, atomic-free: slot = offs[dst] + chunkcum[dst] + LDS-rank
__global__ __launch_bounds__(256) void k_scatlds(
    const int* __restrict__ sF, const int* __restrict__ dF,
    const int* __restrict__ sRB, const int* __restrict__ dRB,
    const int* __restrict__ sR, const int* __restrict__ dR,
    const int* __restrict__ offs, const u16* __restrict__ chunkcum,
    int* __restrict__ csr) {
  __shared__ unsigned h[WIN / 2];          // rank counters, 50 KB
  int c = blockIdx.x, g = blockIdx.y, t = threadIdx.x;
  int a = g >> 1, lo = (g & 1) * WIN;
  for (int i = t; i < WIN / 2; i += 256) h[i] = 0;
  __syncthreads();
  const int* s = (a == 0) ? sF : (a == 1) ? sRB : sR;
  const int* d = (a == 0) ? dF : (a == 1) ? dRB : dR;
  int base = a * NN;
  const u16* cc = chunkcum + ((size_t)g * CHUNKS + c) * WIN;
  int st = c * CHUNK, en = st + CHUNK;
  for (int e = st + t; e < en; e += 256) {
    int dd = d[e];
    unsigned u = (unsigned)(dd - lo);
    if (u < (unsigned)WIN) {
      unsigned sh = (u & 1) * 16;
      unsigned old = atomicAdd(&h[u >> 1], 1u << sh);
      int r = (int)((old >> sh) & 0xffffu);
      csr[offs[base + dd] + (int)cc[u] + r] = s[e];
    }
  }
}

// 6 weight transposes fused: dst[n*256+k] = f2b(src[k*N+n]), K=256 rows
__global__ void k_tpose6(const float* __restrict__ W1f, const float* __restrict__ W1rt,
                         const float* __restrict__ W1rb, const float* __restrict__ W2f,
                         const float* __restrict__ W2rt, const float* __restrict__ W2rb,
                         u16* __restrict__ Bt1u, u16* __restrict__ Bt1i,
                         u16* __restrict__ Bt2u, u16* __restrict__ Bt2i) {
  int a = blockIdx.y;
  const float* src; u16* dst; int N;
  switch (a) {
    case 0: src = W1f;  dst = Bt1u;         N = 256; break;
    case 1: src = W1rt; dst = Bt1u + 65536; N = 256; break;
    case 2: src = W1rb; dst = Bt1i;         N = 256; break;
    case 3: src = W2f;  dst = Bt2u;         N = 128; break;
    case 4: src = W2rt; dst = Bt2u + 32768; N = 128; break;
    default: src = W2rb; dst = Bt2i;        N = 128; break;
  }
  int i = blockIdx.x * 256 + threadIdx.x;
  if (i < 256 * N) {
    int n = i >> 8, k = i & 255;
    dst[i] = f2b(src[(size_t)k * N + n]);
  }
}

// ---------------- GEMM: C[M,Ntot] = A[M,256] @ Bt[Ntot,256]^T, epilogue row-scale ----------------
template <bool AF32>
__global__ __launch_bounds__(256) void k_gemm(
    const void* __restrict__ A, const u16* __restrict__ Bt, u16* __restrict__ C,
    int M, int Ntot, const float* __restrict__ rs0, const float* __restrict__ rs1, int splitN) {
  __shared__ alignas(16) u16 As[128 * 64];
  __shared__ alignas(16) u16 Bs[128 * 64];
  const int tid = threadIdx.x;
  const int mBase = blockIdx.x * 128;
  const int nBase = blockIdx.y * 128;
  const int w = tid >> 6, lane = tid & 63;
  const int wm = w & 1, wn = w >> 1;
  const int lr = lane & 15, quad = lane >> 4;
  floatx4 acc[4][4] = {};
  for (int kb = 0; kb < 256; kb += 64) {
    uint4 va[4], vb[4];
#pragma unroll
    for (int c = 0; c < 4; ++c) {
      int idx = c * 256 + tid;
      int row = idx >> 3;
      int col8 = (idx & 7) * 8;
      int gr = mBase + row; if (gr > M - 1) gr = M - 1;
      if constexpr (AF32) {
        const float* ap = (const float*)A + (size_t)gr * 256 + kb + col8;
        float4 f0 = *(const float4*)ap;
        float4 f1 = *(const float4*)(ap + 4);
        va[c] = make_uint4(
            (unsigned)f2b(f0.x) | ((unsigned)f2b(f0.y) << 16),
            (unsigned)f2b(f0.z) | ((unsigned)f2b(f0.w) << 16),
            (unsigned)f2b(f1.x) | ((unsigned)f2b(f1.y) << 16),
            (unsigned)f2b(f1.z) | ((unsigned)f2b(f1.w) << 16));
      } else {
        va[c] = *(const uint4*)((const u16*)A + (size_t)gr * 256 + kb + col8);
      }
      vb[c] = *(const uint4*)(Bt + (size_t)(nBase + row) * 256 + kb + col8);
    }
#pragma unroll
    for (int c = 0; c < 4; ++c) {
      int idx = c * 256 + tid;
      *(uint4*)(&As[idx * 8]) = va[c];
      *(uint4*)(&Bs[idx * 8]) = vb[c];
    }
    __syncthreads();
#pragma unroll
    for (int ks = 0; ks < 2; ++ks) {
      bf16x8 fa[4], fb[4];
#pragma unroll
      for (int m = 0; m < 4; ++m)
        fa[m] = *(const bf16x8*)(&As[(wm * 64 + m * 16 + lr) * 64 + ks * 32 + quad * 8]);
#pragma unroll
      for (int n = 0; n < 4; ++n)
        fb[n] = *(const bf16x8*)(&Bs[(wn * 64 + n * 16 + lr) * 64 + ks * 32 + quad * 8]);
#pragma unroll
      for (int m = 0; m < 4; ++m)
#pragma unroll
        for (int n = 0; n < 4; ++n)
          acc[m][n] = __builtin_amdgcn_mfma_f32_16x16x32_bf16(fa[m], fb[n], acc[m][n], 0, 0, 0);
    }
    __syncthreads();
  }
#pragma unroll
  for (int n = 0; n < 4; ++n) {
    int cg = nBase + wn * 64 + n * 16 + lr;
    const float* rs = (cg < splitN) ? rs0 : rs1;
#pragma unroll
    for (int m = 0; m < 4; ++m) {
      int rb_ = mBase + wm * 64 + m * 16 + quad * 4;
#pragma unroll
      for (int r = 0; r < 4; ++r) {
        int rg = rb_ + r;
        if (rg < M) C[(size_t)rg * Ntot + cg] = f2b(acc[m][n][r] * rs[rg]);
      }
    }
  }
}

// ---------------- SpMM, XCD-pinned column slices ----------------
// slice = blockIdx.x % NS and HW round-robins consecutive blockIdx across the
// 8 XCDs, so XCD x only ever gathers feature columns of slice (x % NS): its
// L2 working set is NN*SC*2B per table (3.2 MB at SC=32) instead of 25.6 MB.
// Within a block: 64 threads = (64/GL) groups of GL lanes; each group owns one
// dst and walks its edge list with 4 loads in flight per relation (R0's proven
// deep-MLP batch structure). csr is re-read NS times (streaming, cheap).

__device__ __forceinline__ void acc8(float* acc, uint2 v) {
  acc[0] += b2f(v.x & 0xffffu);
  acc[1] += b2f(v.x >> 16);
  acc[2] += b2f(v.y & 0xffffu);
  acc[3] += b2f(v.y >> 16);
}

template <int GL, int NS, bool RELU, bool OUT32, bool TWO>
__global__ __launch_bounds__(64) void k_slice(
    const u16* __restrict__ fA, int sA, int oA,
    const u16* __restrict__ fB, int sB, int oB,
    const int* __restrict__ csr, const int* __restrict__ offs, int baseA, int baseB,
    const float* __restrict__ rsA, const float* __restrict__ rsB,
    const float* __restrict__ bA, const float* __restrict__ bB,
    void* __restrict__ outv, size_t outBase, int sOut) {
  constexpr int SC = GL * 4;            // bf16 columns per slice (64B @ GL=8)
  constexpr int DPB = 64 / GL;          // dsts per block
  const int bid = blockIdx.x;
  const int slice = bid % NS;           // -> fixed XCD via %8 round-robin
  const int grp = bid / NS;
  const int lane = threadIdx.x;
  const int g = lane / GL, sub = lane % GL;
  const int d = grp * DPB + g;          // grid sized so d < NN always

  int eA = offs[baseA + d], enA = offs[baseA + d + 1];
  const u16* pA = fA + oA + slice * SC + sub * 4;
  float a0[4] = {}, a1[4] = {}, b0[4] = {}, b1[4] = {};
  int eB = 0, enB = 0;
  const u16* pB = nullptr;
  if constexpr (TWO) {
    eB = offs[baseB + d]; enB = offs[baseB + d + 1];
    pB = fB + oB + slice * SC + sub * 4;
  }

  if constexpr (TWO) {
    // fused phase: 8 feature loads in flight per group
    while (eA + 4 <= enA && eB + 4 <= enB) {
      int ia[4], ib[4];
      uint2 va[4], vb[4];
#pragma unroll
      for (int k = 0; k < 4; ++k) ia[k] = clampi(csr[eA + k]);
#pragma unroll
      for (int k = 0; k < 4; ++k) ib[k] = clampi(csr[eB + k]);
#pragma unroll
      for (int k = 0; k < 4; ++k) va[k] = *(const uint2*)(pA + (size_t)ia[k] * sA);
#pragma unroll
      for (int k = 0; k < 4; ++k) vb[k] = *(const uint2*)(pB + (size_t)ib[k] * sB);
#pragma unroll
      for (int k = 0; k < 4; ++k) acc8((k & 1) ? a1 : a0, va[k]);
#pragma unroll
      for (int k = 0; k < 4; ++k) acc8((k & 1) ? b1 : b0, vb[k]);
      eA += 4; eB += 4;
    }
  }
  // drain A
  for (; eA + 4 <= enA; eA += 4) {
    int ia[4]; uint2 va[4];
#pragma unroll
    for (int k = 0; k < 4; ++k) ia[k] = clampi(csr[eA + k]);
#pragma unroll
    for (int k = 0; k < 4; ++k) va[k] = *(const uint2*)(pA + (size_t)ia[k] * sA);
#pragma unroll
    for (int k = 0; k < 4; ++k) acc8((k & 1) ? a1 : a0, va[k]);
  }
  for (; eA < enA; ++eA) acc8(a0, *(const uint2*)(pA + (size_t)clampi(csr[eA]) * sA));
  if constexpr (TWO) {
    // drain B
    for (; eB + 4 <= enB; eB += 4) {
      int ib[4]; uint2 vb[4];
#pragma unroll
      for (int k = 0; k < 4; ++k) ib[k] = clampi(csr[eB + k]);
#pragma unroll
      for (int k = 0; k < 4; ++k) vb[k] = *(const uint2*)(pB + (size_t)ib[k] * sB);
#pragma unroll
      for (int k = 0; k < 4; ++k) acc8((k & 1) ? b1 : b0, vb[k]);
    }
    for (; eB < enB; ++eB) acc8(b0, *(const uint2*)(pB + (size_t)clampi(csr[eB]) * sB));
  }

  const int col = slice * SC + sub * 4;
  float ra = rsA[d];
  float4 bv = *(const float4*)(bA + col);
  float xv[4];
#pragma unroll
  for (int v = 0; v < 4; ++v)
    xv[v] = (a0[v] + a1[v]) * ra + ((const float*)&bv)[v];
  if constexpr (TWO) {
    float rb = rsB[d];
    float4 bw = *(const float4*)(bB + col);
#pragma unroll
    for (int v = 0; v < 4; ++v)
      xv[v] = 0.5f * (xv[v] + (b0[v] + b1[v]) * rb + ((const float*)&bw)[v]);
  }
#pragma unroll
  for (int v = 0; v < 4; ++v)
    if (RELU) xv[v] = fmaxf(xv[v], 0.f);
  size_t o = outBase + (size_t)d * sOut + col;
  if constexpr (OUT32) {
    *(float4*)(&((float*)outv)[o]) = make_float4(xv[0], xv[1], xv[2], xv[3]);
  } else {
    uint2 pk;
    pk.x = (unsigned)f2b(xv[0]) | ((unsigned)f2b(xv[1]) << 16);
    pk.y = (unsigned)f2b(xv[2]) | ((unsigned)f2b(xv[3]) << 16);
    *(uint2*)(&((u16*)outv)[o]) = pk;
  }
}

extern "C" void kernel_launch(void* const* d_in, const int* in_sizes, int n_in,
                              void* d_out, int out_size, void* d_ws, size_t ws_size,
                              hipStream_t stream) {
  (void)in_sizes; (void)n_in; (void)out_size;
  const float* x_user = (const float*)d_in[0];
  const float* x_item = (const float*)d_in[1];
  const float* W1f  = (const float*)d_in[2];  const float* b1f  = (const float*)d_in[3];
  const float* W1rt = (const float*)d_in[4];  const float* b1rt = (const float*)d_in[5];
  const float* W1rb = (const float*)d_in[6];  const float* b1rb = (const float*)d_in[7];
  const float* W2f  = (const float*)d_in[8];  const float* b2fo = (const float*)d_in[9];
  const float* W2rt = (const float*)d_in[10]; const float* b2rt = (const float*)d_in[11];
  const float* W2rb = (const float*)d_in[12]; const float* b2rb = (const float*)d_in[13];
  const int* srcF  = (const int*)d_in[14]; const int* dstF  = (const int*)d_in[15];
  const int* srcR  = (const int*)d_in[16]; const int* dstR  = (const int*)d_in[17];
  const int* srcRB = (const int*)d_in[18]; const int* dstRB = (const int*)d_in[19];

  // ---- workspace layout (bytes) ----
  // DI/R   : [0, 1200000)           300000 i32 -> f32 in place
  // offs   : [1800064, 2400068)     150001 i32
  // csr    : [2400128, 12000128)    2400000 i32  (first 588 B double as scan partials)
  // Bt1u/Bt1i/Bt2u/Bt2i bf16        [12000128, 12589952)
  // featA  : [12589952, 63789952)   [50000,512] bf16
  //          scratch (pre-GEMM): partial u16 12*32*25000 @featA+0 (19.2MB),
  //                              chunkcum u16 6*32*25000 @featA+19.2MB (9.6MB)
  // featB  : [63789952, 89389952)   [50000,256]
  // h_u    : [89389952, 114989952)  [50000,256]
  if (ws_size < 114989952u) return;

  char* ws = (char*)d_ws;
  int*   DI     = (int*)ws;
  float* R      = (float*)ws;
  int*   offs   = (int*)(ws + 1800064);
  int*   csr    = (int*)(ws + 2400128);
  int*   partials = csr;                    // scan scratch, free until k_scatlds
  u16*   Bt1u   = (u16*)(ws + 12000128);
  u16*   Bt1i   = (u16*)(ws + 12262272);
  u16*   Bt2u   = (u16*)(ws + 12393344);
  u16*   Bt2i   = (u16*)(ws + 12524416);
  u16*   featA  = (u16*)(ws + 12589952);
  u16*   featB  = (u16*)(ws + 63789952);
  u16*   h_u    = (u16*)(ws + 89389952);
  u16*   h_i    = featB;
  u16*   feat2rb = featA + (size_t)50000 * 256;
  u16*   hpart  = featA;                    // 12*32*25000 u16, dead before GEMM1
  u16*   chunkcum = featA + (size_t)12 * CHUNKS * WIN;  // 6*32*25000 u16

  k_hist<<<dim3(CHUNKS, 12), 256, 0, stream>>>(dstF, dstRB, dstR, srcF, srcR, srcRB, hpart);
  k_hreduce<<<dim3(98, 12), 256, 0, stream>>>(hpart, chunkcum, DI);
  k_scan1<<<147, 1024, 0, stream>>>(DI, offs, partials);
  k_scan2<<<1, 256, 0, stream>>>(partials);
  k_scan3<<<147, 1024, 0, stream>>>(offs, partials);
  k_rsq<<<(300000 + 255) / 256, 256, 0, stream>>>(DI, 300000);
  k_scatlds<<<dim3(CHUNKS, 6), 256, 0, stream>>>(srcF, dstF, srcRB, dstRB, srcR, dstR,
                                                 offs, chunkcum, csr);
  k_tpose6<<<dim3(256, 6), 256, 0, stream>>>(W1f, W1rt, W1rb, W2f, W2rt, W2rb,
                                             Bt1u, Bt1i, Bt2u, Bt2i);

  // layer 1 GEMMs (rsqrt(out_deg) row scale commutes with @W; applied in epilogue)
  k_gemm<true><<<dim3(391, 4), 256, 0, stream>>>(x_user, Bt1u, featA, 50000, 512,
                                                 R + 150000, R + 200000, 256);
  k_gemm<true><<<dim3(391, 2), 256, 0, stream>>>(x_item, Bt1i, featB, 50000, 256,
                                                 R + 250000, R + 250000, 256);

  // layer 1 aggregation (bf16 stores into ws)
  // u-side: 2 tables (featA cols 0..255, featB), GL=8 -> SC=32, 8 slices, 8 dst/blk
  k_slice<8, 8, true, false, true><<<50000, 64, 0, stream>>>(
      featA, 512, 0, featB, 256, 0, csr, offs, 0, 50000,
      R, R + 50000, b1f, b1rb, h_u, 0, 256);
  // i-side: 1 table (featA cols 256..511): 3.2MB/XCD, fully L2-resident
  k_slice<8, 8, true, false, false><<<50000, 64, 0, stream>>>(
      featA, 512, 256, nullptr, 0, 0, csr, offs, 100000, 0,
      R + 100000, nullptr, b1rt, nullptr, h_i, 0, 256);

  // layer 2 GEMMs (A = bf16 ws buffers)
  k_gemm<false><<<dim3(391, 2), 256, 0, stream>>>(h_u, Bt2u, featA, 50000, 256,
                                                  R + 150000, R + 200000, 128);
  k_gemm<false><<<dim3(391, 1), 256, 0, stream>>>(h_i, Bt2i, feat2rb, 50000, 128,
                                                  R + 250000, R + 250000, 128);

  // layer 2 aggregation -> d_out (fp32)
  // u-side: 2 tables x 128 cols: GL=4 -> SC=16, 8 slices -> 1.6+1.6MB/XCD resident
  k_slice<4, 8, false, true, true><<<25000, 64, 0, stream>>>(
      featA, 256, 0, feat2rb, 128, 0, csr, offs, 0, 50000,
      R, R + 50000, b2fo, b2rb, d_out, 0, 128);
  // i-side: 1 table (featA cols 128..255): GL=8 -> SC=32, 4 slices -> 3.2MB/XCD
  k_slice<8, 4, false, true, false><<<25000, 64, 0, stream>>>(
      featA, 256, 128, nullptr, 0, 0, csr, offs, 100000, 0,
      R + 100000, nullptr, b2rt, nullptr, d_out, (size_t)50000 * 128, 128);
}

// Round 5
// 795.228 us; speedup vs baseline: 1.6563x; 1.2712x over previous
//
#include <hip/hip_runtime.h>

typedef unsigned short u16;
typedef __bf16 bf16x8 __attribute__((ext_vector_type(8)));
typedef float floatx4 __attribute__((ext_vector_type(4)));

#define NE 800000
#define NN 50000
#define CHUNKS 32
#define CHUNK (NE / CHUNKS)   // 25000
#define WIN 25000             // histogram window per segment (2 windows per array)

__device__ __forceinline__ float b2f(unsigned u) { return __uint_as_float(u << 16); }
__device__ __forceinline__ u16 f2b(float f) {
  unsigned x = __float_as_uint(f);
  x += 0x7fffu + ((x >> 16) & 1u);
  return (u16)(x >> 16);
}
__device__ __forceinline__ int clampi(int s) {
  return (s < 0) ? 0 : (s > NN - 1 ? NN - 1 : s);
}

// ---------------- histogram degrees (LDS, atomic-free in HBM) ----------------
// segment g in [0,12): array a=g>>1, window r=g&1 covering idx in [r*WIN,(r+1)*WIN)
// arrays: 0=dstF 1=dstRB 2=dstR 3=srcF 4=srcR 5=srcRB  (matches DI layout below)
__global__ __launch_bounds__(256) void k_hist(
    const int* __restrict__ dF, const int* __restrict__ dRB, const int* __restrict__ dR,
    const int* __restrict__ sF, const int* __restrict__ sR, const int* __restrict__ sRB,
    u16* __restrict__ partial) {
  __shared__ unsigned h[WIN / 2];          // packed u16 pairs, 50 KB
  int c = blockIdx.x, g = blockIdx.y, t = threadIdx.x;
  int a = g >> 1, lo = (g & 1) * WIN;
  for (int i = t; i < WIN / 2; i += 256) h[i] = 0;
  __syncthreads();
  const int* idx = (a == 0) ? dF : (a == 1) ? dRB : (a == 2) ? dR
                 : (a == 3) ? sF : (a == 4) ? sR : sRB;
  int st = c * CHUNK, en = st + CHUNK;
  for (int e = st + t; e < en; e += 256) {
    unsigned u = (unsigned)(idx[e] - lo);
    if (u < (unsigned)WIN) atomicAdd(&h[u >> 1], 1u << ((u & 1) * 16));
  }
  __syncthreads();
  unsigned* po = (unsigned*)(partial + ((size_t)g * CHUNKS + c) * WIN);
  for (int i = t; i < WIN / 2; i += 256) po[i] = h[i];
}

// partials -> DI counts; byproduct: exclusive per-chunk cumsum for relations (g<6)
__global__ __launch_bounds__(256) void k_hreduce(const u16* __restrict__ partial,
                                                 u16* __restrict__ chunkcum,
                                                 int* __restrict__ DI) {
  int i = blockIdx.x * 256 + threadIdx.x;
  int g = blockIdx.y;
  if (i >= WIN) return;
  const u16* p = partial + (size_t)g * CHUNKS * WIN + i;
  u16* cc = chunkcum + (size_t)g * CHUNKS * WIN + i;   // only meaningful for g<6
  int run = 0;
#pragma unroll
  for (int c = 0; c < CHUNKS; ++c) {
    if (g < 6) cc[(size_t)c * WIN] = (u16)run;
    run += p[(size_t)c * WIN];
  }
  int a = g >> 1, r = g & 1;
  DI[a * NN + r * WIN + i] = run;
}

// parallel exclusive scan over 150000 counts -> offs[0..150000]
__global__ __launch_bounds__(1024) void k_scan1(const int* __restrict__ cnt,
                                                int* __restrict__ offs,
                                                int* __restrict__ partials) {
  __shared__ int tmp[1024];
  int t = threadIdx.x, i = blockIdx.x * 1024 + t;
  int c = (i < 150000) ? cnt[i] : 0;
  tmp[t] = c; __syncthreads();
  for (int off = 1; off < 1024; off <<= 1) {
    int v = (t >= off) ? tmp[t - off] : 0;
    __syncthreads();
    tmp[t] += v;
    __syncthreads();
  }
  if (i <= 150000) offs[i] = tmp[t] - c;
  if (t == 1023) partials[blockIdx.x] = tmp[1023];
}

__global__ __launch_bounds__(256) void k_scan2(int* __restrict__ partials) {
  __shared__ int tmp[256];
  int t = threadIdx.x;
  int c = (t < 147) ? partials[t] : 0;
  tmp[t] = c; __syncthreads();
  for (int off = 1; off < 256; off <<= 1) {
    int v = (t >= off) ? tmp[t - off] : 0;
    __syncthreads();
    tmp[t] += v;
    __syncthreads();
  }
  if (t < 147) partials[t] = tmp[t] - c;
}

__global__ __launch_bounds__(1024) void k_scan3(int* __restrict__ offs,
                                                const int* __restrict__ partials) {
  int i = blockIdx.x * 1024 + threadIdx.x;
  if (i <= 150000) offs[i] += partials[blockIdx.x];
}

__global__ void k_rsq(int* __restrict__ DI, int n) {
  int i = blockIdx.x * 256 + threadIdx.x;
  if (i < n) {
    float v = (float)DI[i];
    ((float*)DI)[i] = rsqrtf(fmaxf(v, 1.f));
  }
}

// CSR scatter, atomic-free: slot = offs[dst] + chunkcum[dst] + LDS-rank
__global__ __launch_bounds__(256) void k_scatlds(
    const int* __restrict__ sF, const int* __restrict__ dF,
    const int* __restrict__ sRB, const int* __restrict__ dRB,
    const int* __restrict__ sR, const int* __restrict__ dR,
    const int* __restrict__ offs, const u16* __restrict__ chunkcum,
    int* __restrict__ csr) {
  __shared__ unsigned h[WIN / 2];          // rank counters, 50 KB
  int c = blockIdx.x, g = blockIdx.y, t = threadIdx.x;
  int a = g >> 1, lo = (g & 1) * WIN;
  for (int i = t; i < WIN / 2; i += 256) h[i] = 0;
  __syncthreads();
  const int* s = (a == 0) ? sF : (a == 1) ? sRB : sR;
  const int* d = (a == 0) ? dF : (a == 1) ? dRB : dR;
  int base = a * NN;
  const u16* cc = chunkcum + ((size_t)g * CHUNKS + c) * WIN;
  int st = c * CHUNK, en = st + CHUNK;
  for (int e = st + t; e < en; e += 256) {
    int dd = d[e];
    unsigned u = (unsigned)(dd - lo);
    if (u < (unsigned)WIN) {
      unsigned sh = (u & 1) * 16;
      unsigned old = atomicAdd(&h[u >> 1], 1u << sh);
      int r = (int)((old >> sh) & 0xffffu);
      csr[offs[base + dd] + (int)cc[u] + r] = s[e];
    }
  }
}

// 6 weight transposes fused: dst[n*256+k] = f2b(src[k*N+n]), K=256 rows
__global__ void k_tpose6(const float* __restrict__ W1f, const float* __restrict__ W1rt,
                         const float* __restrict__ W1rb, const float* __restrict__ W2f,
                         const float* __restrict__ W2rt, const float* __restrict__ W2rb,
                         u16* __restrict__ Bt1u, u16* __restrict__ Bt1i,
                         u16* __restrict__ Bt2u, u16* __restrict__ Bt2i) {
  int a = blockIdx.y;
  const float* src; u16* dst; int N;
  switch (a) {
    case 0: src = W1f;  dst = Bt1u;         N = 256; break;
    case 1: src = W1rt; dst = Bt1u + 65536; N = 256; break;
    case 2: src = W1rb; dst = Bt1i;         N = 256; break;
    case 3: src = W2f;  dst = Bt2u;         N = 128; break;
    case 4: src = W2rt; dst = Bt2u + 32768; N = 128; break;
    default: src = W2rb; dst = Bt2i;        N = 128; break;
  }
  int i = blockIdx.x * 256 + threadIdx.x;
  if (i < 256 * N) {
    int n = i >> 8, k = i & 255;
    dst[i] = f2b(src[(size_t)k * N + n]);
  }
}

// ---------------- GEMM: C[M,Ntot] = A[M,256] @ Bt[Ntot,256]^T, epilogue row-scale ----------------
template <bool AF32>
__global__ __launch_bounds__(256) void k_gemm(
    const void* __restrict__ A, const u16* __restrict__ Bt, u16* __restrict__ C,
    int M, int Ntot, const float* __restrict__ rs0, const float* __restrict__ rs1, int splitN) {
  __shared__ alignas(16) u16 As[128 * 64];
  __shared__ alignas(16) u16 Bs[128 * 64];
  const int tid = threadIdx.x;
  const int mBase = blockIdx.x * 128;
  const int nBase = blockIdx.y * 128;
  const int w = tid >> 6, lane = tid & 63;
  const int wm = w & 1, wn = w >> 1;
  const int lr = lane & 15, quad = lane >> 4;
  floatx4 acc[4][4] = {};
  for (int kb = 0; kb < 256; kb += 64) {
    uint4 va[4], vb[4];
#pragma unroll
    for (int c = 0; c < 4; ++c) {
      int idx = c * 256 + tid;
      int row = idx >> 3;
      int col8 = (idx & 7) * 8;
      int gr = mBase + row; if (gr > M - 1) gr = M - 1;
      if constexpr (AF32) {
        const float* ap = (const float*)A + (size_t)gr * 256 + kb + col8;
        float4 f0 = *(const float4*)ap;
        float4 f1 = *(const float4*)(ap + 4);
        va[c] = make_uint4(
            (unsigned)f2b(f0.x) | ((unsigned)f2b(f0.y) << 16),
            (unsigned)f2b(f0.z) | ((unsigned)f2b(f0.w) << 16),
            (unsigned)f2b(f1.x) | ((unsigned)f2b(f1.y) << 16),
            (unsigned)f2b(f1.z) | ((unsigned)f2b(f1.w) << 16));
      } else {
        va[c] = *(const uint4*)((const u16*)A + (size_t)gr * 256 + kb + col8);
      }
      vb[c] = *(const uint4*)(Bt + (size_t)(nBase + row) * 256 + kb + col8);
    }
#pragma unroll
    for (int c = 0; c < 4; ++c) {
      int idx = c * 256 + tid;
      *(uint4*)(&As[idx * 8]) = va[c];
      *(uint4*)(&Bs[idx * 8]) = vb[c];
    }
    __syncthreads();
#pragma unroll
    for (int ks = 0; ks < 2; ++ks) {
      bf16x8 fa[4], fb[4];
#pragma unroll
      for (int m = 0; m < 4; ++m)
        fa[m] = *(const bf16x8*)(&As[(wm * 64 + m * 16 + lr) * 64 + ks * 32 + quad * 8]);
#pragma unroll
      for (int n = 0; n < 4; ++n)
        fb[n] = *(const bf16x8*)(&Bs[(wn * 64 + n * 16 + lr) * 64 + ks * 32 + quad * 8]);
#pragma unroll
      for (int m = 0; m < 4; ++m)
#pragma unroll
        for (int n = 0; n < 4; ++n)
          acc[m][n] = __builtin_amdgcn_mfma_f32_16x16x32_bf16(fa[m], fb[n], acc[m][n], 0, 0, 0);
    }
    __syncthreads();
  }
#pragma unroll
  for (int n = 0; n < 4; ++n) {
    int cg = nBase + wn * 64 + n * 16 + lr;
    const float* rs = (cg < splitN) ? rs0 : rs1;
#pragma unroll
    for (int m = 0; m < 4; ++m) {
      int rb_ = mBase + wm * 64 + m * 16 + quad * 4;
#pragma unroll
      for (int r = 0; r < 4; ++r) {
        int rg = rb_ + r;
        if (rg < M) C[(size_t)rg * Ntot + cg] = f2b(acc[m][n][r] * rs[rg]);
      }
    }
  }
}

// ---------------- SpMM, XCD-phase-rotated 128B column slices ----------------
// Slice = 64 bf16 cols = 128 B = one L2 line (no half-line waste, unlike the
// 64 B slices of the previous attempt). Each block reads its REAL XCD id
// (s_getreg HW_REG_XCC_ID, HW-verified on gfx950) and visits the NS slices in
// rotated order s=(xcd+k)&(NS-1). Coverage of every (dst, slice) is complete
// by construction -- XCC_ID only affects ORDER, never correctness. At any
// phase, a slice is served by ~2 XCDs (those with equal xcd&(NS-1)), cutting
// per-line fetch multiplicity from ~8 to ~2 and keeping the per-phase hot set
// line-clean. Inner loop = R0's proven 4+4-deep batched walk (MLP preserved:
// 16-lane groups, 8 B/lane, 32 loads in flight per wave).

__device__ __forceinline__ void acc4f(float* acc, uint2 v) {
  acc[0] += b2f(v.x & 0xffffu);
  acc[1] += b2f(v.x >> 16);
  acc[2] += b2f(v.y & 0xffffu);
  acc[3] += b2f(v.y >> 16);
}

template <int NS, bool RELU, bool OUT32, bool TWO>
__global__ __launch_bounds__(64) void k_xs(
    const u16* __restrict__ fA, int sA, int oA,
    const u16* __restrict__ fB, int sB, int oB,
    const int* __restrict__ csr, const int* __restrict__ offs, int baseA, int baseB,
    const float* __restrict__ rsA, const float* __restrict__ rsB,
    const float* __restrict__ bA, const float* __restrict__ bB,
    void* __restrict__ outv, size_t outBase, int sOut) {
  const int lane = threadIdx.x;
  const int grp = lane >> 4, sub = lane & 15;   // 4 groups x 16 lanes
  const int dbase = blockIdx.x * 8 + grp * 2;   // 2 dsts per group
  unsigned xcd;
  asm volatile("s_getreg_b32 %0, hwreg(HW_REG_XCC_ID)" : "=s"(xcd));
  xcd &= 7u;

  for (int k = 0; k < NS; ++k) {
    const int s = (int)((xcd + (unsigned)k) & (unsigned)(NS - 1));
    const int colb = s * 64 + sub * 4;          // 4 bf16 cols per lane
    const u16* pA = fA + oA + colb;
    const u16* pB = fB + oB + colb;             // unused if !TWO (fB=fA dummy)

#pragma unroll
    for (int j = 0; j < 2; ++j) {
      const int d = dbase + j;
      float a0[4] = {}, a1[4] = {}, b0[4] = {}, b1[4] = {};
      int eA = offs[baseA + d], enA = offs[baseA + d + 1];
      int eB = 0, enB = 0;
      if constexpr (TWO) { eB = offs[baseB + d]; enB = offs[baseB + d + 1]; }

      if constexpr (TWO) {
        // fused phase: 8 feature loads in flight per group
        while (eA + 4 <= enA && eB + 4 <= enB) {
          int ia[4], ib[4];
          uint2 va[4], vb[4];
#pragma unroll
          for (int q = 0; q < 4; ++q) ia[q] = clampi(csr[eA + q]);
#pragma unroll
          for (int q = 0; q < 4; ++q) ib[q] = clampi(csr[eB + q]);
#pragma unroll
          for (int q = 0; q < 4; ++q) va[q] = *(const uint2*)(pA + (size_t)ia[q] * sA);
#pragma unroll
          for (int q = 0; q < 4; ++q) vb[q] = *(const uint2*)(pB + (size_t)ib[q] * sB);
#pragma unroll
          for (int q = 0; q < 4; ++q) acc4f((q & 1) ? a1 : a0, va[q]);
#pragma unroll
          for (int q = 0; q < 4; ++q) acc4f((q & 1) ? b1 : b0, vb[q]);
          eA += 4; eB += 4;
        }
      }
      // drain A
      for (; eA + 4 <= enA; eA += 4) {
        int ia[4]; uint2 va[4];
#pragma unroll
        for (int q = 0; q < 4; ++q) ia[q] = clampi(csr[eA + q]);
#pragma unroll
        for (int q = 0; q < 4; ++q) va[q] = *(const uint2*)(pA + (size_t)ia[q] * sA);
#pragma unroll
        for (int q = 0; q < 4; ++q) acc4f((q & 1) ? a1 : a0, va[q]);
      }
      for (; eA < enA; ++eA) acc4f(a0, *(const uint2*)(pA + (size_t)clampi(csr[eA]) * sA));
      if constexpr (TWO) {
        for (; eB + 4 <= enB; eB += 4) {
          int ib[4]; uint2 vb[4];
#pragma unroll
          for (int q = 0; q < 4; ++q) ib[q] = clampi(csr[eB + q]);
#pragma unroll
          for (int q = 0; q < 4; ++q) vb[q] = *(const uint2*)(pB + (size_t)ib[q] * sB);
#pragma unroll
          for (int q = 0; q < 4; ++q) acc4f((q & 1) ? b1 : b0, vb[q]);
        }
        for (; eB < enB; ++eB) acc4f(b0, *(const uint2*)(pB + (size_t)clampi(csr[eB]) * sB));
      }

      // epilogue for this (dst, slice)
      float ra = rsA[d];
      float4 bv = *(const float4*)(bA + colb);
      float xv[4];
#pragma unroll
      for (int v = 0; v < 4; ++v)
        xv[v] = (a0[v] + a1[v]) * ra + ((const float*)&bv)[v];
      if constexpr (TWO) {
        float rb = rsB[d];
        float4 bw = *(const float4*)(bB + colb);
#pragma unroll
        for (int v = 0; v < 4; ++v)
          xv[v] = 0.5f * (xv[v] + (b0[v] + b1[v]) * rb + ((const float*)&bw)[v]);
      }
#pragma unroll
      for (int v = 0; v < 4; ++v)
        if (RELU) xv[v] = fmaxf(xv[v], 0.f);
      size_t o = outBase + (size_t)d * sOut + colb;
      if constexpr (OUT32) {
        *(float4*)(&((float*)outv)[o]) = make_float4(xv[0], xv[1], xv[2], xv[3]);
      } else {
        uint2 pk;
        pk.x = (unsigned)f2b(xv[0]) | ((unsigned)f2b(xv[1]) << 16);
        pk.y = (unsigned)f2b(xv[2]) | ((unsigned)f2b(xv[3]) << 16);
        *(uint2*)(&((u16*)outv)[o]) = pk;
      }
    }
  }
}

extern "C" void kernel_launch(void* const* d_in, const int* in_sizes, int n_in,
                              void* d_out, int out_size, void* d_ws, size_t ws_size,
                              hipStream_t stream) {
  (void)in_sizes; (void)n_in; (void)out_size;
  const float* x_user = (const float*)d_in[0];
  const float* x_item = (const float*)d_in[1];
  const float* W1f  = (const float*)d_in[2];  const float* b1f  = (const float*)d_in[3];
  const float* W1rt = (const float*)d_in[4];  const float* b1rt = (const float*)d_in[5];
  const float* W1rb = (const float*)d_in[6];  const float* b1rb = (const float*)d_in[7];
  const float* W2f  = (const float*)d_in[8];  const float* b2fo = (const float*)d_in[9];
  const float* W2rt = (const float*)d_in[10]; const float* b2rt = (const float*)d_in[11];
  const float* W2rb = (const float*)d_in[12]; const float* b2rb = (const float*)d_in[13];
  const int* srcF  = (const int*)d_in[14]; const int* dstF  = (const int*)d_in[15];
  const int* srcR  = (const int*)d_in[16]; const int* dstR  = (const int*)d_in[17];
  const int* srcRB = (const int*)d_in[18]; const int* dstRB = (const int*)d_in[19];

  // ---- workspace layout (bytes) ----
  // DI/R   : [0, 1200000)           300000 i32 -> f32 in place
  // offs   : [1800064, 2400068)     150001 i32
  // csr    : [2400128, 12000128)    2400000 i32  (first 588 B double as scan partials)
  // Bt1u/Bt1i/Bt2u/Bt2i bf16        [12000128, 12589952)
  // featA  : [12589952, 63789952)   [50000,512] bf16
  //          scratch (pre-GEMM): partial u16 12*32*25000 @featA+0 (19.2MB),
  //                              chunkcum u16 6*32*25000 @featA+19.2MB (9.6MB)
  // featB  : [63789952, 89389952)   [50000,256]
  // h_u    : [89389952, 114989952)  [50000,256]
  if (ws_size < 114989952u) return;

  char* ws = (char*)d_ws;
  int*   DI     = (int*)ws;
  float* R      = (float*)ws;
  int*   offs   = (int*)(ws + 1800064);
  int*   csr    = (int*)(ws + 2400128);
  int*   partials = csr;                    // scan scratch, free until k_scatlds
  u16*   Bt1u   = (u16*)(ws + 12000128);
  u16*   Bt1i   = (u16*)(ws + 12262272);
  u16*   Bt2u   = (u16*)(ws + 12393344);
  u16*   Bt2i   = (u16*)(ws + 12524416);
  u16*   featA  = (u16*)(ws + 12589952);
  u16*   featB  = (u16*)(ws + 63789952);
  u16*   h_u    = (u16*)(ws + 89389952);
  u16*   h_i    = featB;
  u16*   feat2rb = featA + (size_t)50000 * 256;
  u16*   hpart  = featA;                    // 12*32*25000 u16, dead before GEMM1
  u16*   chunkcum = featA + (size_t)12 * CHUNKS * WIN;  // 6*32*25000 u16

  k_hist<<<dim3(CHUNKS, 12), 256, 0, stream>>>(dstF, dstRB, dstR, srcF, srcR, srcRB, hpart);
  k_hreduce<<<dim3(98, 12), 256, 0, stream>>>(hpart, chunkcum, DI);
  k_scan1<<<147, 1024, 0, stream>>>(DI, offs, partials);
  k_scan2<<<1, 256, 0, stream>>>(partials);
  k_scan3<<<147, 1024, 0, stream>>>(offs, partials);
  k_rsq<<<(300000 + 255) / 256, 256, 0, stream>>>(DI, 300000);
  k_scatlds<<<dim3(CHUNKS, 6), 256, 0, stream>>>(srcF, dstF, srcRB, dstRB, srcR, dstR,
                                                 offs, chunkcum, csr);
  k_tpose6<<<dim3(256, 6), 256, 0, stream>>>(W1f, W1rt, W1rb, W2f, W2rt, W2rb,
                                             Bt1u, Bt1i, Bt2u, Bt2i);

  // layer 1 GEMMs (rsqrt(out_deg) row scale commutes with @W; applied in epilogue)
  k_gemm<true><<<dim3(391, 4), 256, 0, stream>>>(x_user, Bt1u, featA, 50000, 512,
                                                 R + 150000, R + 200000, 256);
  k_gemm<true><<<dim3(391, 2), 256, 0, stream>>>(x_item, Bt1i, featB, 50000, 256,
                                                 R + 250000, R + 250000, 256);

  // layer 1 aggregation (bf16 stores into ws)
  // u-side: featA cols 0..255 (rel follows) + featB (rel ratedby), NS=4 slices
  k_xs<4, true, false, true><<<6250, 64, 0, stream>>>(
      featA, 512, 0, featB, 256, 0, csr, offs, 0, 50000,
      R, R + 50000, b1f, b1rb, h_u, 0, 256);
  // i-side: featA cols 256..511 (rel rates), NS=4
  k_xs<4, true, false, false><<<6250, 64, 0, stream>>>(
      featA, 512, 256, featA, 512, 256, csr, offs, 100000, 0,
      R + 100000, nullptr, b1rt, nullptr, h_i, 0, 256);

  // layer 2 GEMMs (A = bf16 ws buffers)
  k_gemm<false><<<dim3(391, 2), 256, 0, stream>>>(h_u, Bt2u, featA, 50000, 256,
                                                  R + 150000, R + 200000, 128);
  k_gemm<false><<<dim3(391, 1), 256, 0, stream>>>(h_i, Bt2i, feat2rb, 50000, 128,
                                                  R + 250000, R + 250000, 128);

  // layer 2 aggregation -> d_out (fp32)
  // u-side: featA cols 0..127 (follows) + feat2rb (ratedby), NS=2 slices
  k_xs<2, false, true, true><<<6250, 64, 0, stream>>>(
      featA, 256, 0, feat2rb, 128, 0, csr, offs, 0, 50000,
      R, R + 50000, b2fo, b2rb, d_out, 0, 128);
  // i-side: featA cols 128..255 (rates), NS=2
  k_xs<2, false, true, false><<<6250, 64, 0, stream>>>(
      featA, 256, 128, featA, 256, 128, csr, offs, 100000, 0,
      R + 100000, nullptr, b2rt, nullptr, d_out, (size_t)50000 * 128, 128);
}

// Round 6
// 734.957 us; speedup vs baseline: 1.7922x; 1.0820x over previous
//
#include <hip/hip_runtime.h>

typedef unsigned short u16;
typedef __bf16 bf16x8 __attribute__((ext_vector_type(8)));
typedef float floatx4 __attribute__((ext_vector_type(4)));

#define NE 800000
#define NN 50000
#define CHUNKS 32
#define CHUNK (NE / CHUNKS)   // 25000
#define WIN 25000             // histogram window per segment (2 windows per array)

__device__ __forceinline__ float b2f(unsigned u) { return __uint_as_float(u << 16); }
__device__ __forceinline__ u16 f2b(float f) {
  unsigned x = __float_as_uint(f);
  x += 0x7fffu + ((x >> 16) & 1u);
  return (u16)(x >> 16);
}

// async global->LDS, 16B per lane (gfx950). LDS dest must be
// wave-uniform-base + lane*16 -- our As/Bs staging layout satisfies this.
__device__ __forceinline__ void gload_lds16(const void* g, void* l) {
  __builtin_amdgcn_global_load_lds(
      (const __attribute__((address_space(1))) unsigned int*)g,
      (__attribute__((address_space(3))) unsigned int*)l, 16, 0, 0);
}

// ---------------- histogram degrees (LDS, atomic-free in HBM) ----------------
// segment g in [0,12): array a=g>>1, window r=g&1 covering idx in [r*WIN,(r+1)*WIN)
// arrays: 0=dstF 1=dstRB 2=dstR 3=srcF 4=srcR 5=srcRB  (matches DI layout below)
__global__ __launch_bounds__(256) void k_hist(
    const int* __restrict__ dF, const int* __restrict__ dRB, const int* __restrict__ dR,
    const int* __restrict__ sF, const int* __restrict__ sR, const int* __restrict__ sRB,
    u16* __restrict__ partial) {
  __shared__ unsigned h[WIN / 2];          // packed u16 pairs, 50 KB
  int c = blockIdx.x, g = blockIdx.y, t = threadIdx.x;
  int a = g >> 1, lo = (g & 1) * WIN;
  for (int i = t; i < WIN / 2; i += 256) h[i] = 0;
  __syncthreads();
  const int* idx = (a == 0) ? dF : (a == 1) ? dRB : (a == 2) ? dR
                 : (a == 3) ? sF : (a == 4) ? sR : sRB;
  int st = c * CHUNK, en = st + CHUNK;
  for (int e = st + t; e < en; e += 256) {
    unsigned u = (unsigned)(idx[e] - lo);
    if (u < (unsigned)WIN) atomicAdd(&h[u >> 1], 1u << ((u & 1) * 16));
  }
  __syncthreads();
  unsigned* po = (unsigned*)(partial + ((size_t)g * CHUNKS + c) * WIN);
  for (int i = t; i < WIN / 2; i += 256) po[i] = h[i];
}

// partials -> DI counts; byproduct: exclusive per-chunk cumsum for relations (g<6)
__global__ __launch_bounds__(256) void k_hreduce(const u16* __restrict__ partial,
                                                 u16* __restrict__ chunkcum,
                                                 int* __restrict__ DI) {
  int i = blockIdx.x * 256 + threadIdx.x;
  int g = blockIdx.y;
  if (i >= WIN) return;
  const u16* p = partial + (size_t)g * CHUNKS * WIN + i;
  u16* cc = chunkcum + (size_t)g * CHUNKS * WIN + i;   // only meaningful for g<6
  int run = 0;
#pragma unroll
  for (int c = 0; c < CHUNKS; ++c) {
    if (g < 6) cc[(size_t)c * WIN] = (u16)run;
    run += p[(size_t)c * WIN];
  }
  int a = g >> 1, r = g & 1;
  DI[a * NN + r * WIN + i] = run;
}

// parallel exclusive scan over 150000 counts -> offs[0..150000]
__global__ __launch_bounds__(1024) void k_scan1(const int* __restrict__ cnt,
                                                int* __restrict__ offs,
                                                int* __restrict__ partials) {
  __shared__ int tmp[1024];
  int t = threadIdx.x, i = blockIdx.x * 1024 + t;
  int c = (i < 150000) ? cnt[i] : 0;
  tmp[t] = c; __syncthreads();
  for (int off = 1; off < 1024; off <<= 1) {
    int v = (t >= off) ? tmp[t - off] : 0;
    __syncthreads();
    tmp[t] += v;
    __syncthreads();
  }
  if (i <= 150000) offs[i] = tmp[t] - c;
  if (t == 1023) partials[blockIdx.x] = tmp[1023];
}

__global__ __launch_bounds__(256) void k_scan2(int* __restrict__ partials) {
  __shared__ int tmp[256];
  int t = threadIdx.x;
  int c = (t < 147) ? partials[t] : 0;
  tmp[t] = c; __syncthreads();
  for (int off = 1; off < 256; off <<= 1) {
    int v = (t >= off) ? tmp[t - off] : 0;
    __syncthreads();
    tmp[t] += v;
    __syncthreads();
  }
  if (t < 147) partials[t] = tmp[t] - c;
}

__global__ __launch_bounds__(1024) void k_scan3(int* __restrict__ offs,
                                                const int* __restrict__ partials) {
  int i = blockIdx.x * 1024 + threadIdx.x;
  if (i <= 150000) offs[i] += partials[blockIdx.x];
}

__global__ void k_rsq(int* __restrict__ DI, int n) {
  int i = blockIdx.x * 256 + threadIdx.x;
  if (i < n) {
    float v = (float)DI[i];
    ((float*)DI)[i] = rsqrtf(fmaxf(v, 1.f));
  }
}

// CSR scatter, atomic-free: slot = offs[dst] + chunkcum[dst] + LDS-rank
__global__ __launch_bounds__(256) void k_scatlds(
    const int* __restrict__ sF, const int* __restrict__ dF,
    const int* __restrict__ sRB, const int* __restrict__ dRB,
    const int* __restrict__ sR, const int* __restrict__ dR,
    const int* __restrict__ offs, const u16* __restrict__ chunkcum,
    int* __restrict__ csr) {
  __shared__ unsigned h[WIN / 2];          // rank counters, 50 KB
  int c = blockIdx.x, g = blockIdx.y, t = threadIdx.x;
  int a = g >> 1, lo = (g & 1) * WIN;
  for (int i = t; i < WIN / 2; i += 256) h[i] = 0;
  __syncthreads();
  const int* s = (a == 0) ? sF : (a == 1) ? sRB : sR;
  const int* d = (a == 0) ? dF : (a == 1) ? dRB : dR;
  int base = a * NN;
  const u16* cc = chunkcum + ((size_t)g * CHUNKS + c) * WIN;
  int st = c * CHUNK, en = st + CHUNK;
  for (int e = st + t; e < en; e += 256) {
    int dd = d[e];
    unsigned u = (unsigned)(dd - lo);
    if (u < (unsigned)WIN) {
      unsigned sh = (u & 1) * 16;
      unsigned old = atomicAdd(&h[u >> 1], 1u << sh);
      int r = (int)((old >> sh) & 0xffffu);
      csr[offs[base + dd] + (int)cc[u] + r] = s[e];
    }
  }
}

// 6 weight transposes fused: dst[n*256+k] = f2b(src[k*N+n]), K=256 rows
__global__ void k_tpose6(const float* __restrict__ W1f, const float* __restrict__ W1rt,
                         const float* __restrict__ W1rb, const float* __restrict__ W2f,
                         const float* __restrict__ W2rt, const float* __restrict__ W2rb,
                         u16* __restrict__ Bt1u, u16* __restrict__ Bt1i,
                         u16* __restrict__ Bt2u, u16* __restrict__ Bt2i) {
  int a = blockIdx.y;
  const float* src; u16* dst; int N;
  switch (a) {
    case 0: src = W1f;  dst = Bt1u;         N = 256; break;
    case 1: src = W1rt; dst = Bt1u + 65536; N = 256; break;
    case 2: src = W1rb; dst = Bt1i;         N = 256; break;
    case 3: src = W2f;  dst = Bt2u;         N = 128; break;
    case 4: src = W2rt; dst = Bt2u + 32768; N = 128; break;
    default: src = W2rb; dst = Bt2i;        N = 128; break;
  }
  int i = blockIdx.x * 256 + threadIdx.x;
  if (i < 256 * N) {
    int n = i >> 8, k = i & 255;
    dst[i] = f2b(src[(size_t)k * N + n]);
  }
}

// fp32 -> bf16 cast of the two input feature matrices (done once, so GEMMs
// run the pure-bf16 global_load_lds path and A is not re-read as fp32 per
// N-tile). y=0: x_user -> xbU, y=1: x_item -> xbI. 50000*256 each.
__global__ __launch_bounds__(256) void k_cast(const float* __restrict__ xu,
                                              const float* __restrict__ xi,
                                              u16* __restrict__ xbU,
                                              u16* __restrict__ xbI) {
  const float* x = blockIdx.y ? xi : xu;
  u16* xb = blockIdx.y ? xbI : xbU;
  int i = blockIdx.x * 256 + threadIdx.x;          // 4 elems per thread
  if (i < (NN * 256) / 4) {
    float4 f = *(const float4*)(x + (size_t)i * 4);
    uint2 pk;
    pk.x = (unsigned)f2b(f.x) | ((unsigned)f2b(f.y) << 16);
    pk.y = (unsigned)f2b(f.z) | ((unsigned)f2b(f.w) << 16);
    *(uint2*)(xb + (size_t)i * 4) = pk;
  }
}

// ---------------- GEMM: C[M,Ntot] = A[M,256] @ Bt[Ntot,256]^T, epilogue row-scale ----
// A is bf16 [M,256]. Staging via global_load_lds width=16 (async, no VGPR
// round-trip); As/Bs layout is wave-uniform-base + lane*16 so direct-to-LDS
// is legal. MFMA inner loop unchanged.
__global__ __launch_bounds__(256) void k_gemm(
    const u16* __restrict__ A, const u16* __restrict__ Bt, u16* __restrict__ C,
    int M, int Ntot, const float* __restrict__ rs0, const float* __restrict__ rs1, int splitN) {
  __shared__ alignas(16) u16 As[128 * 64];
  __shared__ alignas(16) u16 Bs[128 * 64];
  const int tid = threadIdx.x;
  const int mBase = blockIdx.x * 128;
  const int nBase = blockIdx.y * 128;
  const int w = tid >> 6, lane = tid & 63;
  const int wm = w & 1, wn = w >> 1;
  const int lr = lane & 15, quad = lane >> 4;
  floatx4 acc[4][4] = {};
  for (int kb = 0; kb < 256; kb += 64) {
#pragma unroll
    for (int c = 0; c < 4; ++c) {
      int idx = c * 256 + tid;
      int row = idx >> 3;
      int col8 = (idx & 7) * 8;
      int gr = mBase + row; if (gr > M - 1) gr = M - 1;
      gload_lds16(A + (size_t)gr * 256 + kb + col8, &As[idx * 8]);
      gload_lds16(Bt + (size_t)(nBase + row) * 256 + kb + col8, &Bs[idx * 8]);
    }
    __syncthreads();
#pragma unroll
    for (int ks = 0; ks < 2; ++ks) {
      bf16x8 fa[4], fb[4];
#pragma unroll
      for (int m = 0; m < 4; ++m)
        fa[m] = *(const bf16x8*)(&As[(wm * 64 + m * 16 + lr) * 64 + ks * 32 + quad * 8]);
#pragma unroll
      for (int n = 0; n < 4; ++n)
        fb[n] = *(const bf16x8*)(&Bs[(wn * 64 + n * 16 + lr) * 64 + ks * 32 + quad * 8]);
#pragma unroll
      for (int m = 0; m < 4; ++m)
#pragma unroll
        for (int n = 0; n < 4; ++n)
          acc[m][n] = __builtin_amdgcn_mfma_f32_16x16x32_bf16(fa[m], fb[n], acc[m][n], 0, 0, 0);
    }
    __syncthreads();
  }
#pragma unroll
  for (int n = 0; n < 4; ++n) {
    int cg = nBase + wn * 64 + n * 16 + lr;
    const float* rs = (cg < splitN) ? rs0 : rs1;
#pragma unroll
    for (int m = 0; m < 4; ++m) {
      int rb_ = mBase + wm * 64 + m * 16 + quad * 4;
#pragma unroll
      for (int r = 0; r < 4; ++r) {
        int rg = rb_ + r;
        if (rg < M) C[(size_t)rg * Ntot + cg] = f2b(acc[m][n][r] * rs[rg]);
      }
    }
  }
}

// ---------------- SpMM (CSR by dst), fp32 accumulate, edge-unroll x2 ----------------
// R0-proven structure (measured at its fabric roofline: dur ~ FETCH/3.85TB/s).
template <int VEC>
__device__ __forceinline__ void addv(float* acc, const u16* p) {
  if constexpr (VEC == 4) {
    uint2 v = *(const uint2*)p;
    acc[0] += b2f(v.x & 0xffffu); acc[1] += b2f(v.x >> 16);
    acc[2] += b2f(v.y & 0xffffu); acc[3] += b2f(v.y >> 16);
  } else {
    unsigned v = *(const unsigned*)p;
    acc[0] += b2f(v & 0xffffu); acc[1] += b2f(v >> 16);
  }
}

__device__ __forceinline__ int clampi(int s) {
  return (s < 0) ? 0 : (s > NN - 1 ? NN - 1 : s);
}

template <int VEC>
__device__ __forceinline__ void gather(float* acc0, float* acc1, const u16* f, int stride,
                                       int off, const int* __restrict__ csr, int st, int en,
                                       int lane) {
  int e = st;
  for (; e + 1 < en; e += 2) {
    int i0 = clampi(csr[e]), i1 = clampi(csr[e + 1]);
    addv<VEC>(acc0, f + (size_t)i0 * stride + off + lane * VEC);
    addv<VEC>(acc1, f + (size_t)i1 * stride + off + lane * VEC);
  }
  if (e < en) addv<VEC>(acc0, f + (size_t)clampi(csr[e]) * stride + off + lane * VEC);
}

template <int VEC, bool RELU, bool OUT32>
__global__ __launch_bounds__(64) void k_spmm2(
    const u16* __restrict__ fA, int sA, int oA,
    const u16* __restrict__ fB, int sB, int oB,
    const int* __restrict__ csr, const int* __restrict__ offs, int baseA, int baseB,
    const float* __restrict__ rsA, const float* __restrict__ rsB,
    const float* __restrict__ bA, const float* __restrict__ bB,
    void* __restrict__ outv, size_t outBase, int sOut) {
  int d = blockIdx.x, lane = threadIdx.x;
  float a0[VEC] = {}, a1[VEC] = {}, b0[VEC] = {}, b1[VEC] = {};
  gather<VEC>(a0, a1, fA, sA, oA, csr, offs[baseA + d], offs[baseA + d + 1], lane);
  gather<VEC>(b0, b1, fB, sB, oB, csr, offs[baseB + d], offs[baseB + d + 1], lane);
  float ra = rsA[d], rb = rsB[d];
  size_t o = outBase + (size_t)d * sOut + lane * VEC;
#pragma unroll
  for (int v = 0; v < VEC; ++v) {
    float x = 0.5f * ((a0[v] + a1[v]) * ra + bA[lane * VEC + v]
                      + (b0[v] + b1[v]) * rb + bB[lane * VEC + v]);
    if (RELU) x = fmaxf(x, 0.f);
    if (OUT32) ((float*)outv)[o + v] = x;
    else       ((u16*)outv)[o + v] = f2b(x);
  }
}

template <int VEC, bool RELU, bool OUT32>
__global__ __launch_bounds__(64) void k_spmm1(
    const u16* __restrict__ fA, int sA, int oA,
    const int* __restrict__ csr, const int* __restrict__ offs, int baseA,
    const float* __restrict__ rsA, const float* __restrict__ bA,
    void* __restrict__ outv, size_t outBase, int sOut) {
  int d = blockIdx.x, lane = threadIdx.x;
  float a0[VEC] = {}, a1[VEC] = {};
  gather<VEC>(a0, a1, fA, sA, oA, csr, offs[baseA + d], offs[baseA + d + 1], lane);
  float ra = rsA[d];
  size_t o = outBase + (size_t)d * sOut + lane * VEC;
#pragma unroll
  for (int v = 0; v < VEC; ++v) {
    float x = (a0[v] + a1[v]) * ra + bA[lane * VEC + v];
    if (RELU) x = fmaxf(x, 0.f);
    if (OUT32) ((float*)outv)[o + v] = x;
    else       ((u16*)outv)[o + v] = f2b(x);
  }
}

extern "C" void kernel_launch(void* const* d_in, const int* in_sizes, int n_in,
                              void* d_out, int out_size, void* d_ws, size_t ws_size,
                              hipStream_t stream) {
  (void)in_sizes; (void)n_in; (void)out_size;
  const float* x_user = (const float*)d_in[0];
  const float* x_item = (const float*)d_in[1];
  const float* W1f  = (const float*)d_in[2];  const float* b1f  = (const float*)d_in[3];
  const float* W1rt = (const float*)d_in[4];  const float* b1rt = (const float*)d_in[5];
  const float* W1rb = (const float*)d_in[6];  const float* b1rb = (const float*)d_in[7];
  const float* W2f  = (const float*)d_in[8];  const float* b2fo = (const float*)d_in[9];
  const float* W2rt = (const float*)d_in[10]; const float* b2rt = (const float*)d_in[11];
  const float* W2rb = (const float*)d_in[12]; const float* b2rb = (const float*)d_in[13];
  const int* srcF  = (const int*)d_in[14]; const int* dstF  = (const int*)d_in[15];
  const int* srcR  = (const int*)d_in[16]; const int* dstR  = (const int*)d_in[17];
  const int* srcRB = (const int*)d_in[18]; const int* dstRB = (const int*)d_in[19];

  // ---- workspace layout (bytes) ----
  // DI/R   : [0, 1200000)           300000 i32 -> f32 in place
  // offs   : [1800064, 2400068)     150001 i32
  // csr    : [2400128, 12000128)    2400000 i32  (first 588 B double as scan partials)
  // Bt1u/Bt1i/Bt2u/Bt2i bf16        [12000128, 12589952)
  // featA  : [12589952, 63789952)   [50000,512] bf16
  //          scratch (pre-GEMM): partial u16 12*32*25000 @featA+0 (19.2MB),
  //                              chunkcum u16 6*32*25000 @featA+19.2MB (9.6MB);
  //          xbI bf16 [50000,256] @featA+0 (25.6MB, alive k_cast..GEMM1i only)
  // featB  : [63789952, 89389952)   [50000,256]
  // h_u    : [89389952, 114989952)  [50000,256]; xbU bf16 @h_u (alive until GEMM1u)
  if (ws_size < 114989952u) return;

  char* ws = (char*)d_ws;
  int*   DI     = (int*)ws;
  float* R      = (float*)ws;
  int*   offs   = (int*)(ws + 1800064);
  int*   csr    = (int*)(ws + 2400128);
  int*   partials = csr;                    // scan scratch, free until k_scatlds
  u16*   Bt1u   = (u16*)(ws + 12000128);
  u16*   Bt1i   = (u16*)(ws + 12262272);
  u16*   Bt2u   = (u16*)(ws + 12393344);
  u16*   Bt2i   = (u16*)(ws + 12524416);
  u16*   featA  = (u16*)(ws + 12589952);
  u16*   featB  = (u16*)(ws + 63789952);
  u16*   h_u    = (u16*)(ws + 89389952);
  u16*   h_i    = featB;
  u16*   feat2rb = featA + (size_t)50000 * 256;
  u16*   hpart  = featA;                    // 12*32*25000 u16, dead before k_cast
  u16*   chunkcum = featA + (size_t)12 * CHUNKS * WIN;  // 6*32*25000 u16
  u16*   xbI    = featA;                    // bf16 x_item, dead after GEMM1i
  u16*   xbU    = h_u;                      // bf16 x_user, dead after GEMM1u

  k_hist<<<dim3(CHUNKS, 12), 256, 0, stream>>>(dstF, dstRB, dstR, srcF, srcR, srcRB, hpart);
  k_hreduce<<<dim3(98, 12), 256, 0, stream>>>(hpart, chunkcum, DI);
  k_scan1<<<147, 1024, 0, stream>>>(DI, offs, partials);
  k_scan2<<<1, 256, 0, stream>>>(partials);
  k_scan3<<<147, 1024, 0, stream>>>(offs, partials);
  k_rsq<<<(300000 + 255) / 256, 256, 0, stream>>>(DI, 300000);
  k_scatlds<<<dim3(CHUNKS, 6), 256, 0, stream>>>(srcF, dstF, srcRB, dstRB, srcR, dstR,
                                                 offs, chunkcum, csr);
  k_tpose6<<<dim3(256, 6), 256, 0, stream>>>(W1f, W1rt, W1rb, W2f, W2rt, W2rb,
                                             Bt1u, Bt1i, Bt2u, Bt2i);
  // cast inputs to bf16 once (xbI overlays featA scratch -> must be after k_scatlds)
  k_cast<<<dim3((NN * 256 / 4 + 255) / 256, 2), 256, 0, stream>>>(x_user, x_item, xbU, xbI);

  // layer 1 GEMMs (rsqrt(out_deg) row scale commutes with @W; applied in epilogue)
  // item first: GEMM1u's featA write overwrites xbI.
  k_gemm<<<dim3(391, 2), 256, 0, stream>>>(xbI, Bt1i, featB, 50000, 256,
                                           R + 250000, R + 250000, 256);
  k_gemm<<<dim3(391, 4), 256, 0, stream>>>(xbU, Bt1u, featA, 50000, 512,
                                           R + 150000, R + 200000, 256);
  // layer 1 aggregation (bf16 stores into ws; h_u write overwrites xbU)
  k_spmm2<4, true, false><<<50000, 64, 0, stream>>>(featA, 512, 0, featB, 256, 0,
                                                    csr, offs, 0, 50000,
                                                    R, R + 50000, b1f, b1rb, h_u, 0, 256);
  k_spmm1<4, true, false><<<50000, 64, 0, stream>>>(featA, 512, 256, csr, offs, 100000,
                                                    R + 100000, b1rt, h_i, 0, 256);
  // layer 2 GEMMs (A = bf16 ws buffers)
  k_gemm<<<dim3(391, 2), 256, 0, stream>>>(h_u, Bt2u, featA, 50000, 256,
                                           R + 150000, R + 200000, 128);
  k_gemm<<<dim3(391, 1), 256, 0, stream>>>(h_i, Bt2i, feat2rb, 50000, 128,
                                           R + 250000, R + 250000, 128);
  // layer 2 aggregation -> d_out (fp32)
  k_spmm2<2, false, true><<<50000, 64, 0, stream>>>(featA, 256, 0, feat2rb, 128, 0,
                                                    csr, offs, 0, 50000,
                                                    R, R + 50000, b2fo, b2rb, d_out, 0, 128);
  k_spmm1<2, false, true><<<50000, 64, 0, stream>>>(featA, 256, 128, csr, offs, 100000,
                                                    R + 100000, b2rt, d_out, (size_t)50000 * 128, 128);
}

// Round 7
// 693.660 us; speedup vs baseline: 1.8989x; 1.0595x over previous
//
#include <hip/hip_runtime.h>

typedef unsigned short u16;
typedef __bf16 bf16x8 __attribute__((ext_vector_type(8)));
typedef float floatx4 __attribute__((ext_vector_type(4)));

#define NE 800000
#define NN 50000
#define CHUNKS 32
#define CHUNK (NE / CHUNKS)   // 25000
#define WIN 25000             // histogram window per segment (2 windows per array)

__device__ __forceinline__ float b2f(unsigned u) { return __uint_as_float(u << 16); }
__device__ __forceinline__ u16 f2b(float f) {
  unsigned x = __float_as_uint(f);
  x += 0x7fffu + ((x >> 16) & 1u);
  return (u16)(x >> 16);
}

// async global->LDS, 16B per lane (gfx950). LDS dest must be
// wave-uniform-base + lane*16 -- our As/Bs staging layout satisfies this.
__device__ __forceinline__ void gload_lds16(const void* g, void* l) {
  __builtin_amdgcn_global_load_lds(
      (const __attribute__((address_space(1))) unsigned int*)g,
      (__attribute__((address_space(3))) unsigned int*)l, 16, 0, 0);
}

// ---------------- histogram degrees (LDS, atomic-free in HBM) ----------------
__global__ __launch_bounds__(256) void k_hist(
    const int* __restrict__ dF, const int* __restrict__ dRB, const int* __restrict__ dR,
    const int* __restrict__ sF, const int* __restrict__ sR, const int* __restrict__ sRB,
    u16* __restrict__ partial) {
  __shared__ unsigned h[WIN / 2];          // packed u16 pairs, 50 KB
  int c = blockIdx.x, g = blockIdx.y, t = threadIdx.x;
  int a = g >> 1, lo = (g & 1) * WIN;
  for (int i = t; i < WIN / 2; i += 256) h[i] = 0;
  __syncthreads();
  const int* idx = (a == 0) ? dF : (a == 1) ? dRB : (a == 2) ? dR
                 : (a == 3) ? sF : (a == 4) ? sR : sRB;
  int st = c * CHUNK, en = st + CHUNK;
  for (int e = st + t; e < en; e += 256) {
    unsigned u = (unsigned)(idx[e] - lo);
    if (u < (unsigned)WIN) atomicAdd(&h[u >> 1], 1u << ((u & 1) * 16));
  }
  __syncthreads();
  unsigned* po = (unsigned*)(partial + ((size_t)g * CHUNKS + c) * WIN);
  for (int i = t; i < WIN / 2; i += 256) po[i] = h[i];
}

// partials -> DI counts; byproduct: exclusive per-chunk cumsum for relations (g<6)
__global__ __launch_bounds__(256) void k_hreduce(const u16* __restrict__ partial,
                                                 u16* __restrict__ chunkcum,
                                                 int* __restrict__ DI) {
  int i = blockIdx.x * 256 + threadIdx.x;
  int g = blockIdx.y;
  if (i >= WIN) return;
  const u16* p = partial + (size_t)g * CHUNKS * WIN + i;
  u16* cc = chunkcum + (size_t)g * CHUNKS * WIN + i;   // only meaningful for g<6
  int run = 0;
#pragma unroll
  for (int c = 0; c < CHUNKS; ++c) {
    if (g < 6) cc[(size_t)c * WIN] = (u16)run;
    run += p[(size_t)c * WIN];
  }
  int a = g >> 1, r = g & 1;
  DI[a * NN + r * WIN + i] = run;
}

// parallel exclusive scan over 150000 counts -> offs[0..150000]
__global__ __launch_bounds__(1024) void k_scan1(const int* __restrict__ cnt,
                                                int* __restrict__ offs,
                                                int* __restrict__ partials) {
  __shared__ int tmp[1024];
  int t = threadIdx.x, i = blockIdx.x * 1024 + t;
  int c = (i < 150000) ? cnt[i] : 0;
  tmp[t] = c; __syncthreads();
  for (int off = 1; off < 1024; off <<= 1) {
    int v = (t >= off) ? tmp[t - off] : 0;
    __syncthreads();
    tmp[t] += v;
    __syncthreads();
  }
  if (i <= 150000) offs[i] = tmp[t] - c;
  if (t == 1023) partials[blockIdx.x] = tmp[1023];
}

__global__ __launch_bounds__(256) void k_scan2(int* __restrict__ partials) {
  __shared__ int tmp[256];
  int t = threadIdx.x;
  int c = (t < 147) ? partials[t] : 0;
  tmp[t] = c; __syncthreads();
  for (int off = 1; off < 256; off <<= 1) {
    int v = (t >= off) ? tmp[t - off] : 0;
    __syncthreads();
    tmp[t] += v;
    __syncthreads();
  }
  if (t < 147) partials[t] = tmp[t] - c;
}

// scan finalize + rsqrt(deg) fold (was a separate k_rsq launch)
__global__ __launch_bounds__(1024) void k_scan3(int* __restrict__ offs,
                                                const int* __restrict__ partials,
                                                int* __restrict__ DI) {
  int t = threadIdx.x, b = blockIdx.x;
  int i = b * 1024 + t;
  if (i <= 150000) offs[i] += partials[b];
  int j = i * 2;
  if (j < 300000) {
    float v0 = (float)DI[j];
    ((float*)DI)[j] = rsqrtf(fmaxf(v0, 1.f));
    if (j + 1 < 300000) {
      float v1 = (float)DI[j + 1];
      ((float*)DI)[j + 1] = rsqrtf(fmaxf(v1, 1.f));
    }
  }
}

// CSR scatter, atomic-free: slot = offs[dst] + chunkcum[dst] + LDS-rank
__global__ __launch_bounds__(256) void k_scatlds(
    const int* __restrict__ sF, const int* __restrict__ dF,
    const int* __restrict__ sRB, const int* __restrict__ dRB,
    const int* __restrict__ sR, const int* __restrict__ dR,
    const int* __restrict__ offs, const u16* __restrict__ chunkcum,
    int* __restrict__ csr) {
  __shared__ unsigned h[WIN / 2];          // rank counters, 50 KB
  int c = blockIdx.x, g = blockIdx.y, t = threadIdx.x;
  int a = g >> 1, lo = (g & 1) * WIN;
  for (int i = t; i < WIN / 2; i += 256) h[i] = 0;
  __syncthreads();
  const int* s = (a == 0) ? sF : (a == 1) ? sRB : sR;
  const int* d = (a == 0) ? dF : (a == 1) ? dRB : dR;
  int base = a * NN;
  const u16* cc = chunkcum + ((size_t)g * CHUNKS + c) * WIN;
  int st = c * CHUNK, en = st + CHUNK;
  for (int e = st + t; e < en; e += 256) {
    int dd = d[e];
    unsigned u = (unsigned)(dd - lo);
    if (u < (unsigned)WIN) {
      unsigned sh = (u & 1) * 16;
      unsigned old = atomicAdd(&h[u >> 1], 1u << sh);
      int r = (int)((old >> sh) & 0xffffu);
      csr[offs[base + dd] + (int)cc[u] + r] = s[e];
    }
  }
}

// 6 weight transposes fused: dst[n*256+k] = f2b(src[k*N+n]), K=256 rows
__global__ void k_tpose6(const float* __restrict__ W1f, const float* __restrict__ W1rt,
                         const float* __restrict__ W1rb, const float* __restrict__ W2f,
                         const float* __restrict__ W2rt, const float* __restrict__ W2rb,
                         u16* __restrict__ Bt1u, u16* __restrict__ Bt1i,
                         u16* __restrict__ Bt2u, u16* __restrict__ Bt2i) {
  int a = blockIdx.y;
  const float* src; u16* dst; int N;
  switch (a) {
    case 0: src = W1f;  dst = Bt1u;         N = 256; break;
    case 1: src = W1rt; dst = Bt1u + 65536; N = 256; break;
    case 2: src = W1rb; dst = Bt1i;         N = 256; break;
    case 3: src = W2f;  dst = Bt2u;         N = 128; break;
    case 4: src = W2rt; dst = Bt2u + 32768; N = 128; break;
    default: src = W2rb; dst = Bt2i;        N = 128; break;
  }
  int i = blockIdx.x * 256 + threadIdx.x;
  if (i < 256 * N) {
    int n = i >> 8, k = i & 255;
    dst[i] = f2b(src[(size_t)k * N + n]);
  }
}

// fp32 -> bf16 cast of the two input feature matrices (once; GEMMs then run
// the pure-bf16 global_load_lds path). y=0: x_user -> xbU, y=1: x_item -> xbI.
__global__ __launch_bounds__(256) void k_cast(const float* __restrict__ xu,
                                              const float* __restrict__ xi,
                                              u16* __restrict__ xbU,
                                              u16* __restrict__ xbI) {
  const float* x = blockIdx.y ? xi : xu;
  u16* xb = blockIdx.y ? xbI : xbU;
  int i = blockIdx.x * 256 + threadIdx.x;          // 4 elems per thread
  if (i < (NN * 256) / 4) {
    float4 f = *(const float4*)(x + (size_t)i * 4);
    uint2 pk;
    pk.x = (unsigned)f2b(f.x) | ((unsigned)f2b(f.y) << 16);
    pk.y = (unsigned)f2b(f.z) | ((unsigned)f2b(f.w) << 16);
    *(uint2*)(xb + (size_t)i * 4) = pk;
  }
}

// ---------------- paired GEMM: two C[M,*] = A[M,256] @ Bt[*,256]^T in one grid ----
// blockIdx.x = global N-tile (xt < nt0 -> config 0, else config 1);
// blockIdx.y = M-tile. x runs fastest in dispatch order, so consecutive blocks
// share the same A M-tile -> A re-reads are L2/LLC-hot (was 391 blocks apart).
// Body identical to the verified R6 k_gemm (gload_lds width-16 staging).
__global__ __launch_bounds__(256) void k_gemmP(
    const u16* __restrict__ A0, const u16* __restrict__ B0, u16* __restrict__ C0,
    int Nt0, const float* __restrict__ rs00, const float* __restrict__ rs01,
    int sp0, int nt0,
    const u16* __restrict__ A1, const u16* __restrict__ B1, u16* __restrict__ C1,
    int Nt1, const float* __restrict__ rs10, const float* __restrict__ rs11,
    int sp1) {
  __shared__ alignas(16) u16 As[128 * 64];
  __shared__ alignas(16) u16 Bs[128 * 64];
  const int M = NN;
  const int xt = blockIdx.x;
  const u16* A; const u16* Bt; u16* C;
  int Ntot, splitN, nb;
  const float *rs0, *rs1;
  if (xt < nt0) { A = A0; Bt = B0; C = C0; Ntot = Nt0; rs0 = rs00; rs1 = rs01;
                  splitN = sp0; nb = xt; }
  else          { A = A1; Bt = B1; C = C1; Ntot = Nt1; rs0 = rs10; rs1 = rs11;
                  splitN = sp1; nb = xt - nt0; }
  const int tid = threadIdx.x;
  const int mBase = blockIdx.y * 128;
  const int nBase = nb * 128;
  const int w = tid >> 6, lane = tid & 63;
  const int wm = w & 1, wn = w >> 1;
  const int lr = lane & 15, quad = lane >> 4;
  floatx4 acc[4][4] = {};
  for (int kb = 0; kb < 256; kb += 64) {
#pragma unroll
    for (int c = 0; c < 4; ++c) {
      int idx = c * 256 + tid;
      int row = idx >> 3;
      int col8 = (idx & 7) * 8;
      int gr = mBase + row; if (gr > M - 1) gr = M - 1;
      gload_lds16(A + (size_t)gr * 256 + kb + col8, &As[idx * 8]);
      gload_lds16(Bt + (size_t)(nBase + row) * 256 + kb + col8, &Bs[idx * 8]);
    }
    __syncthreads();
#pragma unroll
    for (int ks = 0; ks < 2; ++ks) {
      bf16x8 fa[4], fb[4];
#pragma unroll
      for (int m = 0; m < 4; ++m)
        fa[m] = *(const bf16x8*)(&As[(wm * 64 + m * 16 + lr) * 64 + ks * 32 + quad * 8]);
#pragma unroll
      for (int n = 0; n < 4; ++n)
        fb[n] = *(const bf16x8*)(&Bs[(wn * 64 + n * 16 + lr) * 64 + ks * 32 + quad * 8]);
#pragma unroll
      for (int m = 0; m < 4; ++m)
#pragma unroll
        for (int n = 0; n < 4; ++n)
          acc[m][n] = __builtin_amdgcn_mfma_f32_16x16x32_bf16(fa[m], fb[n], acc[m][n], 0, 0, 0);
    }
    __syncthreads();
  }
#pragma unroll
  for (int n = 0; n < 4; ++n) {
    int cg = nBase + wn * 64 + n * 16 + lr;
    const float* rs = (cg < splitN) ? rs0 : rs1;
#pragma unroll
    for (int m = 0; m < 4; ++m) {
      int rb_ = mBase + wm * 64 + m * 16 + quad * 4;
#pragma unroll
      for (int r = 0; r < 4; ++r) {
        int rg = rb_ + r;
        if (rg < M) C[(size_t)rg * Ntot + cg] = f2b(acc[m][n][r] * rs[rg]);
      }
    }
  }
}

// ---------------- SpMM (CSR by dst), fp32 accumulate, edge-unroll x2 ----------------
// R0-proven gather (measured at its fabric roofline: dur ~ FETCH/3.8TB/s).
// Both per-layer SpMMs merged into one dispatch: blockIdx.y==0 -> two-relation
// u-side, ==1 -> one-relation i-side. Independent tails overlap.
template <int VEC>
__device__ __forceinline__ void addv(float* acc, const u16* p) {
  if constexpr (VEC == 4) {
    uint2 v = *(const uint2*)p;
    acc[0] += b2f(v.x & 0xffffu); acc[1] += b2f(v.x >> 16);
    acc[2] += b2f(v.y & 0xffffu); acc[3] += b2f(v.y >> 16);
  } else {
    unsigned v = *(const unsigned*)p;
    acc[0] += b2f(v & 0xffffu); acc[1] += b2f(v >> 16);
  }
}

__device__ __forceinline__ int clampi(int s) {
  return (s < 0) ? 0 : (s > NN - 1 ? NN - 1 : s);
}

template <int VEC>
__device__ __forceinline__ void gather(float* acc0, float* acc1, const u16* f, int stride,
                                       int off, const int* __restrict__ csr, int st, int en,
                                       int lane) {
  int e = st;
  for (; e + 1 < en; e += 2) {
    int i0 = clampi(csr[e]), i1 = clampi(csr[e + 1]);
    addv<VEC>(acc0, f + (size_t)i0 * stride + off + lane * VEC);
    addv<VEC>(acc1, f + (size_t)i1 * stride + off + lane * VEC);
  }
  if (e < en) addv<VEC>(acc0, f + (size_t)clampi(csr[e]) * stride + off + lane * VEC);
}

template <int VEC, bool RELU, bool OUT32>
__global__ __launch_bounds__(64) void k_spmmL(
    const u16* __restrict__ fA, int sA, int oA,
    const u16* __restrict__ fB, int sB, int oB,
    const u16* __restrict__ fI, int sI, int oI,
    const int* __restrict__ csr, const int* __restrict__ offs,
    const float* __restrict__ rsA, const float* __restrict__ rsB,
    const float* __restrict__ rsI,
    const float* __restrict__ bA, const float* __restrict__ bB,
    const float* __restrict__ bI,
    void* __restrict__ outU, int sOutU,
    void* __restrict__ outI, size_t outIBase, int sOutI) {
  int d = blockIdx.x, lane = threadIdx.x;
  if (blockIdx.y == 0) {
    float a0[VEC] = {}, a1[VEC] = {}, b0[VEC] = {}, b1[VEC] = {};
    gather<VEC>(a0, a1, fA, sA, oA, csr, offs[d], offs[d + 1], lane);
    gather<VEC>(b0, b1, fB, sB, oB, csr, offs[NN + d], offs[NN + d + 1], lane);
    float ra = rsA[d], rb = rsB[d];
    size_t o = (size_t)d * sOutU + lane * VEC;
#pragma unroll
    for (int v = 0; v < VEC; ++v) {
      float x = 0.5f * ((a0[v] + a1[v]) * ra + bA[lane * VEC + v]
                        + (b0[v] + b1[v]) * rb + bB[lane * VEC + v]);
      if (RELU) x = fmaxf(x, 0.f);
      if (OUT32) ((float*)outU)[o + v] = x;
      else       ((u16*)outU)[o + v] = f2b(x);
    }
  } else {
    float a0[VEC] = {}, a1[VEC] = {};
    gather<VEC>(a0, a1, fI, sI, oI, csr, offs[2 * NN + d], offs[2 * NN + d + 1], lane);
    float ra = rsI[d];
    size_t o = outIBase + (size_t)d * sOutI + lane * VEC;
#pragma unroll
    for (int v = 0; v < VEC; ++v) {
      float x = (a0[v] + a1[v]) * ra + bI[lane * VEC + v];
      if (RELU) x = fmaxf(x, 0.f);
      if (OUT32) ((float*)outI)[o + v] = x;
      else       ((u16*)outI)[o + v] = f2b(x);
    }
  }
}

extern "C" void kernel_launch(void* const* d_in, const int* in_sizes, int n_in,
                              void* d_out, int out_size, void* d_ws, size_t ws_size,
                              hipStream_t stream) {
  (void)in_sizes; (void)n_in; (void)out_size;
  const float* x_user = (const float*)d_in[0];
  const float* x_item = (const float*)d_in[1];
  const float* W1f  = (const float*)d_in[2];  const float* b1f  = (const float*)d_in[3];
  const float* W1rt = (const float*)d_in[4];  const float* b1rt = (const float*)d_in[5];
  const float* W1rb = (const float*)d_in[6];  const float* b1rb = (const float*)d_in[7];
  const float* W2f  = (const float*)d_in[8];  const float* b2fo = (const float*)d_in[9];
  const float* W2rt = (const float*)d_in[10]; const float* b2rt = (const float*)d_in[11];
  const float* W2rb = (const float*)d_in[12]; const float* b2rb = (const float*)d_in[13];
  const int* srcF  = (const int*)d_in[14]; const int* dstF  = (const int*)d_in[15];
  const int* srcR  = (const int*)d_in[16]; const int* dstR  = (const int*)d_in[17];
  const int* srcRB = (const int*)d_in[18]; const int* dstRB = (const int*)d_in[19];

  // ---- workspace layout (bytes) ----
  // DI/R   : [0, 1200000)           300000 i32 -> f32 in place
  // offs   : [1800064, 2400068)     150001 i32
  // csr    : [2400128, 12000128)    2400000 i32  (first 588 B double as scan partials)
  // Bt1u/Bt1i/Bt2u/Bt2i bf16        [12000128, 12589952)
  // featA  : [12589952, 63789952)   [50000,512] bf16
  //          scratch (pre-GEMM): hpart u16 12*32*25000 @featA+0 (19.2MB),
  //                              chunkcum u16 6*32*25000 @featA+19.2MB (9.6MB)
  // featB  : [63789952, 89389952)   [50000,256]
  // h_u    : [89389952, 114989952)  [50000,256]; xbU overlay (dead after GEMM-L1)
  // d_out overlays: xbI bf16 [50000,256] @d_out+0 (dead after GEMM-L1),
  //                 h_i bf16 [50000,256] @d_out+25.6MB (dead after GEMM-L2);
  //                 final spmm-L2 overwrites both halves of d_out.
  if (ws_size < 114989952u) return;

  char* ws = (char*)d_ws;
  int*   DI     = (int*)ws;
  float* R      = (float*)ws;
  int*   offs   = (int*)(ws + 1800064);
  int*   csr    = (int*)(ws + 2400128);
  int*   partials = csr;                    // scan scratch, free until k_scatlds
  u16*   Bt1u   = (u16*)(ws + 12000128);
  u16*   Bt1i   = (u16*)(ws + 12262272);
  u16*   Bt2u   = (u16*)(ws + 12393344);
  u16*   Bt2i   = (u16*)(ws + 12524416);
  u16*   featA  = (u16*)(ws + 12589952);
  u16*   featB  = (u16*)(ws + 63789952);
  u16*   h_u    = (u16*)(ws + 89389952);
  u16*   feat2rb = featA + (size_t)50000 * 256;
  u16*   hpart  = featA;                    // 12*32*25000 u16, dead before GEMMs
  u16*   chunkcum = featA + (size_t)12 * CHUNKS * WIN;  // 6*32*25000 u16
  u16*   xbU    = h_u;                      // bf16 x_user, dead after GEMM-L1
  u16*   xbI    = (u16*)d_out;              // bf16 x_item, dead after GEMM-L1
  u16*   h_i    = (u16*)((char*)d_out + 25600000);  // dead after GEMM-L2

  k_hist<<<dim3(CHUNKS, 12), 256, 0, stream>>>(dstF, dstRB, dstR, srcF, srcR, srcRB, hpart);
  k_hreduce<<<dim3(98, 12), 256, 0, stream>>>(hpart, chunkcum, DI);
  k_scan1<<<147, 1024, 0, stream>>>(DI, offs, partials);
  k_scan2<<<1, 256, 0, stream>>>(partials);
  k_scan3<<<147, 1024, 0, stream>>>(offs, partials, DI);
  k_scatlds<<<dim3(CHUNKS, 6), 256, 0, stream>>>(srcF, dstF, srcRB, dstRB, srcR, dstR,
                                                 offs, chunkcum, csr);
  k_tpose6<<<dim3(256, 6), 256, 0, stream>>>(W1f, W1rt, W1rb, W2f, W2rt, W2rb,
                                             Bt1u, Bt1i, Bt2u, Bt2i);
  // cast inputs to bf16 once (xbI overlays d_out; xbU overlays h_u)
  k_cast<<<dim3((NN * 256 / 4 + 255) / 256, 2), 256, 0, stream>>>(x_user, x_item, xbU, xbI);

  // layer 1 GEMMs, one dispatch (rs row-scale commutes with @W; epilogue-applied)
  k_gemmP<<<dim3(6, 391), 256, 0, stream>>>(
      xbU, Bt1u, featA, 512, R + 150000, R + 200000, 256, 4,
      xbI, Bt1i, featB, 256, R + 250000, R + 250000, 256);
  // layer 1 aggregation, one dispatch (u-side -> h_u overwrites xbU; i-side -> h_i)
  k_spmmL<4, true, false><<<dim3(50000, 2), 64, 0, stream>>>(
      featA, 512, 0, featB, 256, 0, featA, 512, 256,
      csr, offs, R, R + 50000, R + 100000, b1f, b1rb, b1rt,
      h_u, 256, h_i, 0, 256);
  // layer 2 GEMMs, one dispatch
  k_gemmP<<<dim3(3, 391), 256, 0, stream>>>(
      h_u, Bt2u, featA, 256, R + 150000, R + 200000, 128, 2,
      h_i, Bt2i, feat2rb, 128, R + 250000, R + 250000, 128);
  // layer 2 aggregation -> d_out (fp32), one dispatch
  k_spmmL<2, false, true><<<dim3(50000, 2), 64, 0, stream>>>(
      featA, 256, 0, feat2rb, 128, 0, featA, 256, 128,
      csr, offs, R, R + 50000, R + 100000, b2fo, b2rb, b2rt,
      d_out, 128, d_out, (size_t)50000 * 128, 128);
}